// Round 3
// baseline (11248.993 us; speedup 1.0000x reference)
//
#include <hip/hip_runtime.h>
#include <stdint.h>

// Problem dims
#define T_   512
#define B_   64
#define E_   512
#define H_   1024
#define G4   4096      // 4*H
#define TCH  128       // T chunk for gates buffer
#define MCH  (TCH*B_)  // 8192 rows per chunk
#define BH   (B_*H_)

typedef __attribute__((ext_vector_type(8))) short short8;
typedef __attribute__((ext_vector_type(4))) float f32x4;

__device__ __forceinline__ unsigned short f2bf(float f) {
  unsigned u = __builtin_bit_cast(unsigned, f);
  u += 0x7FFFu + ((u >> 16) & 1u);
  return (unsigned short)(u >> 16);
}
__device__ __forceinline__ float bf2f(unsigned short h) {
  return __builtin_bit_cast(float, ((unsigned)h) << 16);
}
__device__ __forceinline__ float sigm(float x) { return 1.f / (1.f + __expf(-x)); }
__device__ __forceinline__ float tanh_f(float x) {
  x = fmaxf(x, -30.f);
  float e = __expf(-2.f * x);
  return (1.f - e) / (1.f + e);
}

// perm1: n = (kblk, gate, uu16) -> orig = gate*1024 + kblk*16 + uu
__device__ __forceinline__ int perm1_orig(int n) {
  return ((n >> 4) & 3) * 1024 + (n >> 6) * 16 + (n & 15);
}

// ---------------- prep: weight convert+permute ----------------
__global__ void prep_w_kernel(const float* __restrict__ src, unsigned short* __restrict__ dst,
                              int kshift) {   // K/4 = 1<<kshift; dst pitch = K, perm1
  const int idx = blockIdx.x * 256 + threadIdx.x;
  const int n = idx >> kshift;
  const int k4 = idx & ((1 << kshift) - 1);
  const int K = 4 << kshift;
  const int orig = perm1_orig(n);
  const float4 v = *((const float4*)(src + (size_t)orig * K) + k4);
  uint2 pk;
  pk.x = (unsigned)f2bf(v.x) | ((unsigned)f2bf(v.y) << 16);
  pk.y = (unsigned)f2bf(v.z) | ((unsigned)f2bf(v.w) << 16);
  *((uint2*)(dst + (size_t)n * K) + k4) = pk;
}

// fused L2 weight: dst[4096][2048] perm1 rows; koff=0 <- Wih1, koff=1024 <- Whh1
__global__ void prep_w2_kernel(const float* __restrict__ src, unsigned short* __restrict__ dst,
                               int koff) {
  const int idx = blockIdx.x * 256 + threadIdx.x;  // 4096 blocks
  const int n = idx >> 8;           // row
  const int k4 = idx & 255;         // K/4 = 256
  const int orig = perm1_orig(n);
  const float4 v = *((const float4*)(src + (size_t)orig * 1024) + k4);
  uint2 pk;
  pk.x = (unsigned)f2bf(v.x) | ((unsigned)f2bf(v.y) << 16);
  pk.y = (unsigned)f2bf(v.z) | ((unsigned)f2bf(v.w) << 16);
  *((uint2*)(dst + (size_t)n * 2048 + koff) + k4) = pk;
}

__global__ void prep_bias_kernel(const float* __restrict__ bih0, const float* __restrict__ bhh0,
                                 const float* __restrict__ bih1, const float* __restrict__ bhh1,
                                 float* __restrict__ b0, float* __restrict__ b2) {
  const int n = blockIdx.x * 256 + threadIdx.x;  // 4096
  const int o = perm1_orig(n);
  b0[n] = bih0[o] + bhh0[o];
  b2[n] = bih1[o] + bhh1[o];
}

// ---------------- embedding gather -> bf16 [32768][512] ----------------
__global__ void embed_kernel(const int* __restrict__ tok, const float* __restrict__ emb,
                             unsigned short* __restrict__ xe) {
  const int idx = blockIdx.x * 256 + threadIdx.x;
  const int row = idx >> 7, c4 = idx & 127;
  const int t = tok[row];
  const float4 v = *((const float4*)(emb + (size_t)t * E_) + c4);
  uint2 pk;
  pk.x = (unsigned)f2bf(v.x) | ((unsigned)f2bf(v.y) << 16);
  pk.y = (unsigned)f2bf(v.z) | ((unsigned)f2bf(v.w) << 16);
  *((uint2*)(xe + (size_t)row * E_) + c4) = pk;
}

// ---------------- projection GEMM (layer-1 input proj only) ----------------
__global__ __launch_bounds__(256, 2) void proj_kernel(
    const unsigned short* __restrict__ A, const unsigned short* __restrict__ Bw,
    const float* __restrict__ bias, unsigned short* __restrict__ Cout, int K) {
  __shared__ unsigned short lsA[128 * 32];
  __shared__ unsigned short lsB[128 * 32];
  const int tid = threadIdx.x;
  const int row0 = blockIdx.x * 128;
  const int col0 = blockIdx.y * 128;
  const int w = tid >> 6, l = tid & 63, l16 = l & 15, kq = l >> 4;
  const int wr = w >> 1, wc = w & 1;
  const int sr = tid >> 2, sc = (tid & 3) * 8;
  f32x4 acc[4][4];
#pragma unroll
  for (int m = 0; m < 4; ++m)
#pragma unroll
    for (int n = 0; n < 4; ++n) acc[m][n] = (f32x4){0.f, 0.f, 0.f, 0.f};

  const unsigned short* Ab  = A  + (size_t)(row0 + sr) * K + sc;
  const unsigned short* Ab2 = Ab + (size_t)64 * K;
  const unsigned short* Bb  = Bw + (size_t)(col0 + sr) * K + sc;
  const unsigned short* Bb2 = Bb + (size_t)64 * K;

  for (int k0 = 0; k0 < K; k0 += 32) {
    short8 va0 = *(const short8*)(Ab + k0);
    short8 va1 = *(const short8*)(Ab2 + k0);
    short8 vb0 = *(const short8*)(Bb + k0);
    short8 vb1 = *(const short8*)(Bb2 + k0);
    __syncthreads();
    *(short8*)&lsA[sr * 32 + sc] = va0;
    *(short8*)&lsA[(64 + sr) * 32 + sc] = va1;
    *(short8*)&lsB[sr * 32 + sc] = vb0;
    *(short8*)&lsB[(64 + sr) * 32 + sc] = vb1;
    __syncthreads();
    short8 af[4], bfr[4];
#pragma unroll
    for (int m = 0; m < 4; ++m) af[m] = *(const short8*)&lsA[(wr * 64 + m * 16 + l16) * 32 + kq * 8];
#pragma unroll
    for (int n = 0; n < 4; ++n) bfr[n] = *(const short8*)&lsB[(wc * 64 + n * 16 + l16) * 32 + kq * 8];
#pragma unroll
    for (int m = 0; m < 4; ++m)
#pragma unroll
      for (int n = 0; n < 4; ++n)
        acc[m][n] = __builtin_amdgcn_mfma_f32_16x16x32_bf16(af[m], bfr[n], acc[m][n], 0, 0, 0);
  }
#pragma unroll
  for (int n = 0; n < 4; ++n) {
    const int col = col0 + wc * 64 + n * 16 + l16;
    const float bv = bias[col];
#pragma unroll
    for (int m = 0; m < 4; ++m)
#pragma unroll
      for (int r = 0; r < 4; ++r) {
        const int row = row0 + wr * 64 + m * 16 + kq * 4 + r;
        Cout[(size_t)row * G4 + col] = f2bf(acc[m][n][r] + bv);
      }
  }
}

// ---------------- fused persistent recurrent kernel (decoupled barrier groups) ----------------
// grid = 130: bid 0..63   L1 worker (kblk=bid, 64 perm1 cols, K=1024 from h1[t-1])
//             bid 64..127 L2 worker (j=bid-64, 64 perm1 cols, K=2048 from [h1[t2]; h2[t2-1]])
//             bid 128     L1 leader: scans l1flags -> publishes l1gen
//             bid 129     L2 leader: scans l2flags -> publishes l2gen
// flag semantics: l1flags[i]=v  =>  WG i has published h1[0..v-1]; l1gen = min over group.
__global__ __launch_bounds__(256, 1) void fused_kernel(
    const unsigned short* __restrict__ Whh0p,   // [4096][1024] perm1
    const unsigned short* __restrict__ W2p,     // [4096][2048] perm1
    const unsigned short* __restrict__ xw,      // [S*64][4096] layer-1 gates chunk
    const float* __restrict__ bias2,            // [4096] perm1
    unsigned short* __restrict__ h1buf, unsigned short* __restrict__ h2buf,
    float* __restrict__ c1buf, float* __restrict__ c2buf,
    int t0, int S,
    unsigned* __restrict__ l1flags, unsigned* __restrict__ l2flags,
    unsigned* __restrict__ l1gen, unsigned* __restrict__ l2gen) {
  // 86016 B LDS: forces 1 WG/CU. Exchange area: 16 x 64 x stride-18 floats.
  __shared__ float smem[21504];
  const int tid = threadIdx.x, bid = blockIdx.x;
  const int w = tid >> 6, l = tid & 63, l16 = l & 15, kq = l >> 4;

  if (bid >= 128) {
    // ---------- leaders ----------
    if (w != 0) return;
    const int grp = bid - 128;
    unsigned* f = (grp == 0 ? l1flags : l2flags) + l * 32;   // padded 128B/flag
    unsigned* gen = (grp == 0) ? l1gen : l2gen;
    const int gs = (grp == 0) ? (t0 + 1) : (t0 > 1 ? t0 : 1);
    const int ge = (grp == 0) ? (t0 + S - 1) : (t0 + S - 2);
    for (int g = gs; g <= ge; ++g) {
      for (;;) {
        unsigned v = __hip_atomic_load(f, __ATOMIC_RELAXED, __HIP_MEMORY_SCOPE_AGENT);
        if (__all((int)(v >= (unsigned)g))) break;
        __builtin_amdgcn_s_sleep(1);
      }
      if (l == 0) __hip_atomic_store(gen, (unsigned)g, __ATOMIC_RELEASE, __HIP_MEMORY_SCOPE_AGENT);
    }
    return;
  }

  const int u0 = (tid & 7) * 2;   // unit pair within WG's 16 units
  const int r0 = (tid >> 3) * 2;  // row pair

  if (bid < 64) {
    // ================= layer 1 worker =================
    const int kblk = bid;
    short8 bf[4][8];   // 128 VGPR resident weights: 64 cols x K-slice 256
#pragma unroll
    for (int st = 0; st < 4; ++st) {
      const unsigned short* bp = Whh0p + (size_t)(kblk * 64 + st * 16 + l16) * H_ + w * 256 + kq * 8;
#pragma unroll
      for (int ks = 0; ks < 8; ++ks) bf[st][ks] = *(const short8*)(bp + ks * 32);
    }
    float c00, c01, c10, c11;
    if (t0 == 0) {
      c00 = c01 = c10 = c11 = 0.f;
    } else {
      const float* cb = c1buf + (size_t)r0 * H_ + kblk * 16 + u0;
      c00 = cb[0]; c01 = cb[1]; c10 = cb[H_]; c11 = cb[H_ + 1];
    }
    unsigned xwa[8], xwn[8];
#pragma unroll
    for (int q = 0; q < 8; ++q) xwn[q] = 0;
    if (t0 < T_) {
      const unsigned short* xb = xw + (size_t)r0 * G4 + kblk * 64 + u0;
#pragma unroll
      for (int dr = 0; dr < 2; ++dr)
#pragma unroll
        for (int g = 0; g < 4; ++g) xwa[dr * 4 + g] = *(const unsigned*)(xb + dr * G4 + g * 16);
    }
    for (int s = 0; s < S; ++s) {
      const int t1 = t0 + s;
      if (t1 >= T_) break;
      if (s >= 1) {
        if (tid == 0) {
          while (__hip_atomic_load(l1gen, __ATOMIC_RELAXED, __HIP_MEMORY_SCOPE_AGENT) < (unsigned)t1)
            __builtin_amdgcn_s_sleep(1);
        }
        __syncthreads();
        __builtin_amdgcn_fence(__ATOMIC_ACQUIRE, "agent");
#pragma unroll
        for (int q = 0; q < 8; ++q) xwa[q] = xwn[q];
      }
      f32x4 acc[4][4];
#pragma unroll
      for (int rf = 0; rf < 4; ++rf)
#pragma unroll
        for (int st = 0; st < 4; ++st) acc[rf][st] = (f32x4){0.f, 0.f, 0.f, 0.f};
      if (t1 > 0) {
        const unsigned short* hp = h1buf + (size_t)(t1 - 1) * BH + (size_t)l16 * H_ + w * 256 + kq * 8;
#pragma unroll
        for (int ks = 0; ks < 8; ++ks) {
          short8 a0 = *(const short8*)(hp + ks * 32);
          short8 a1 = *(const short8*)(hp + 16 * H_ + ks * 32);
          short8 a2 = *(const short8*)(hp + 32 * H_ + ks * 32);
          short8 a3 = *(const short8*)(hp + 48 * H_ + ks * 32);
#pragma unroll
          for (int st = 0; st < 4; ++st) {
            acc[0][st] = __builtin_amdgcn_mfma_f32_16x16x32_bf16(a0, bf[st][ks], acc[0][st], 0, 0, 0);
            acc[1][st] = __builtin_amdgcn_mfma_f32_16x16x32_bf16(a1, bf[st][ks], acc[1][st], 0, 0, 0);
            acc[2][st] = __builtin_amdgcn_mfma_f32_16x16x32_bf16(a2, bf[st][ks], acc[2][st], 0, 0, 0);
            acc[3][st] = __builtin_amdgcn_mfma_f32_16x16x32_bf16(a3, bf[st][ks], acc[3][st], 0, 0, 0);
          }
        }
      }
#pragma unroll
      for (int rf = 0; rf < 4; ++rf)
#pragma unroll
        for (int st = 0; st < 4; ++st)
#pragma unroll
          for (int r = 0; r < 4; ++r)
            smem[(size_t)((w * 4 + st) * 64 + rf * 16 + kq * 4 + r) * 18 + l16] = acc[rf][st][r];
      __syncthreads();
      float hv[2][2];
#pragma unroll
      for (int dr = 0; dr < 2; ++dr)
#pragma unroll
        for (int du = 0; du < 2; ++du) {
          const int row = r0 + dr, u = u0 + du;
          float gs[4];
#pragma unroll
          for (int g = 0; g < 4; ++g) {
            gs[g] = smem[(size_t)((0 + g) * 64 + row) * 18 + u]
                  + smem[(size_t)((4 + g) * 64 + row) * 18 + u]
                  + smem[(size_t)((8 + g) * 64 + row) * 18 + u]
                  + smem[(size_t)((12 + g) * 64 + row) * 18 + u]
                  + bf2f((unsigned short)(xwa[dr * 4 + g] >> (du * 16)));
          }
          float iv = sigm(gs[0]), fv = sigm(gs[1]), gv = tanh_f(gs[2]), ov = sigm(gs[3]);
          float& c = dr ? (du ? c11 : c10) : (du ? c01 : c00);
          c = fv * c + iv * gv;
          hv[dr][du] = ov * tanh_f(c);
        }
#pragma unroll
      for (int dr = 0; dr < 2; ++dr) {
        unsigned pk = (unsigned)f2bf(hv[dr][0]) | ((unsigned)f2bf(hv[dr][1]) << 16);
        unsigned* dst = (unsigned*)(h1buf + (size_t)t1 * BH + (size_t)(r0 + dr) * H_ + kblk * 16 + u0);
        __hip_atomic_store(dst, pk, __ATOMIC_RELAXED, __HIP_MEMORY_SCOPE_AGENT);
      }
      if (s + 1 < S) {  // prefetch next xw during sync slack
        const unsigned short* xb = xw + (size_t)(s + 1) * (B_ * G4) + (size_t)r0 * G4 + kblk * 64 + u0;
#pragma unroll
        for (int dr = 0; dr < 2; ++dr)
#pragma unroll
          for (int g = 0; g < 4; ++g) xwn[dr * 4 + g] = *(const unsigned*)(xb + dr * G4 + g * 16);
      }
      __syncthreads();  // drains h-publish stores (vmcnt 0 per wave) before signal
      if (tid == 0)
        __hip_atomic_store(&l1flags[bid * 32], (unsigned)(t1 + 1), __ATOMIC_RELEASE, __HIP_MEMORY_SCOPE_AGENT);
    }
    if (t0 < T_) {
      float* cb = c1buf + (size_t)r0 * H_ + kblk * 16 + u0;
      cb[0] = c00; cb[1] = c01; cb[H_] = c10; cb[H_ + 1] = c11;
    }
  } else {
    // ================= layer 2 worker (fused K=2048) =================
    const int j = bid - 64;
    short8 bf2[4][16];  // 256 VGPR resident weights: 64 cols x K-slice 512
#pragma unroll
    for (int st = 0; st < 4; ++st) {
      const unsigned short* bp = W2p + (size_t)(j * 64 + st * 16 + l16) * 2048 + w * 512 + kq * 8;
#pragma unroll
      for (int ks = 0; ks < 16; ++ks) bf2[st][ks] = *(const short8*)(bp + ks * 32);
    }
    float bias_r[2][4];
#pragma unroll
    for (int du = 0; du < 2; ++du)
#pragma unroll
      for (int g = 0; g < 4; ++g) bias_r[du][g] = bias2[j * 64 + g * 16 + u0 + du];
    float c00, c01, c10, c11;
    if (t0 == 0) {
      c00 = c01 = c10 = c11 = 0.f;
    } else {
      const float* cb = c2buf + (size_t)r0 * H_ + j * 16 + u0;
      c00 = cb[0]; c01 = cb[1]; c10 = cb[H_]; c11 = cb[H_ + 1];
    }
    for (int s = 0; s < S; ++s) {
      const int t2 = t0 + s - 1;
      if (t2 >= T_) break;
      if (t2 >= 0) {
        if (s >= 1) {
          if (tid == 0) {
            while (__hip_atomic_load(l1gen, __ATOMIC_RELAXED, __HIP_MEMORY_SCOPE_AGENT) < (unsigned)(t2 + 1))
              __builtin_amdgcn_s_sleep(1);
            if (t2 >= 1) {
              while (__hip_atomic_load(l2gen, __ATOMIC_RELAXED, __HIP_MEMORY_SCOPE_AGENT) < (unsigned)t2)
                __builtin_amdgcn_s_sleep(1);
            }
          }
          __syncthreads();
          __builtin_amdgcn_fence(__ATOMIC_ACQUIRE, "agent");
        }
        f32x4 acc[4][4];
#pragma unroll
        for (int rf = 0; rf < 4; ++rf)
#pragma unroll
          for (int st = 0; st < 4; ++st) acc[rf][st] = (f32x4){0.f, 0.f, 0.f, 0.f};
        const bool half2 = (w >= 2);   // waves 2,3: A = h2[t2-1]
        if (!half2 || t2 > 0) {
          const unsigned short* ap = half2
              ? (h2buf + (size_t)(t2 - 1) * BH + (size_t)l16 * H_ + (w - 2) * 512 + kq * 8)
              : (h1buf + (size_t)t2 * BH + (size_t)l16 * H_ + w * 512 + kq * 8);
#pragma unroll
          for (int ks = 0; ks < 16; ++ks) {
            short8 a0 = *(const short8*)(ap + ks * 32);
            short8 a1 = *(const short8*)(ap + 16 * H_ + ks * 32);
            short8 a2 = *(const short8*)(ap + 32 * H_ + ks * 32);
            short8 a3 = *(const short8*)(ap + 48 * H_ + ks * 32);
#pragma unroll
            for (int st = 0; st < 4; ++st) {
              acc[0][st] = __builtin_amdgcn_mfma_f32_16x16x32_bf16(a0, bf2[st][ks], acc[0][st], 0, 0, 0);
              acc[1][st] = __builtin_amdgcn_mfma_f32_16x16x32_bf16(a1, bf2[st][ks], acc[1][st], 0, 0, 0);
              acc[2][st] = __builtin_amdgcn_mfma_f32_16x16x32_bf16(a2, bf2[st][ks], acc[2][st], 0, 0, 0);
              acc[3][st] = __builtin_amdgcn_mfma_f32_16x16x32_bf16(a3, bf2[st][ks], acc[3][st], 0, 0, 0);
            }
          }
        }
#pragma unroll
        for (int rf = 0; rf < 4; ++rf)
#pragma unroll
          for (int st = 0; st < 4; ++st)
#pragma unroll
            for (int r = 0; r < 4; ++r)
              smem[(size_t)((w * 4 + st) * 64 + rf * 16 + kq * 4 + r) * 18 + l16] = acc[rf][st][r];
        __syncthreads();
        float hv[2][2];
#pragma unroll
        for (int dr = 0; dr < 2; ++dr)
#pragma unroll
          for (int du = 0; du < 2; ++du) {
            const int row = r0 + dr, u = u0 + du;
            float gs[4];
#pragma unroll
            for (int g = 0; g < 4; ++g) {
              gs[g] = smem[(size_t)((0 + g) * 64 + row) * 18 + u]
                    + smem[(size_t)((4 + g) * 64 + row) * 18 + u]
                    + smem[(size_t)((8 + g) * 64 + row) * 18 + u]
                    + smem[(size_t)((12 + g) * 64 + row) * 18 + u]
                    + bias_r[du][g];
            }
            float iv = sigm(gs[0]), fv = sigm(gs[1]), gv = tanh_f(gs[2]), ov = sigm(gs[3]);
            float& c = dr ? (du ? c11 : c10) : (du ? c01 : c00);
            c = fv * c + iv * gv;
            hv[dr][du] = ov * tanh_f(c);
          }
#pragma unroll
        for (int dr = 0; dr < 2; ++dr) {
          unsigned pk = (unsigned)f2bf(hv[dr][0]) | ((unsigned)f2bf(hv[dr][1]) << 16);
          unsigned* dst = (unsigned*)(h2buf + (size_t)t2 * BH + (size_t)(r0 + dr) * H_ + j * 16 + u0);
          __hip_atomic_store(dst, pk, __ATOMIC_RELAXED, __HIP_MEMORY_SCOPE_AGENT);
        }
        __syncthreads();  // drains h2-publish before signal
        if (tid == 0)
          __hip_atomic_store(&l2flags[j * 32], (unsigned)(t2 + 1), __ATOMIC_RELEASE, __HIP_MEMORY_SCOPE_AGENT);
      }
    }
    if (t0 + S - 2 >= 0) {
      float* cb = c2buf + (size_t)r0 * H_ + j * 16 + u0;
      cb[0] = c00; cb[1] = c01; cb[H_] = c10; cb[H_ + 1] = c11;
    }
  }
}

// ---------------- head ----------------
__global__ void head_kernel(const unsigned short* __restrict__ hl, const float* __restrict__ Wd,
                            const float* __restrict__ bdp, float* __restrict__ out) {
  __shared__ float p[256];
  const int tid = threadIdx.x, b = tid >> 2, q = tid & 3;
  const unsigned short* hr = hl + (size_t)b * H_ + q * 256;
  const float* wd = Wd + q * 256;
  float s = 0.f;
#pragma unroll 4
  for (int j = 0; j < 256; j += 8) {
    short8 v = *(const short8*)(hr + j);
#pragma unroll
    for (int i = 0; i < 8; ++i) s += bf2f((unsigned short)v[i]) * wd[j + i];
  }
  p[tid] = s;
  __syncthreads();
  if (q == 0) {
    float tot = p[tid] + p[tid + 1] + p[tid + 2] + p[tid + 3] + bdp[0];
    out[b] = 10.f * sigm(tot);
  }
}

// ---------------- host ----------------
extern "C" void kernel_launch(void* const* d_in, const int* in_sizes, int n_in,
                              void* d_out, int out_size, void* d_ws, size_t ws_size,
                              hipStream_t stream) {
  const int*   tokens = (const int*)d_in[0];
  const float* emb  = (const float*)d_in[1];
  const float* Wih0 = (const float*)d_in[2];
  const float* Whh0 = (const float*)d_in[3];
  const float* bih0 = (const float*)d_in[4];
  const float* bhh0 = (const float*)d_in[5];
  const float* Wih1 = (const float*)d_in[6];
  const float* Whh1 = (const float*)d_in[7];
  const float* bih1 = (const float*)d_in[8];
  const float* bhh1 = (const float*)d_in[9];
  const float* Wd   = (const float*)d_in[10];
  const float* bd   = (const float*)d_in[11];
  float* out = (float*)d_out;
  char* ws = (char*)d_ws;

  // ws layout (bytes)
  const size_t O_WIH0 = 0;                       // 4 MiB
  const size_t O_WHH0 = O_WIH0 + 4194304;        // 8 MiB
  const size_t O_W2   = O_WHH0 + 8388608;        // 16 MiB
  const size_t O_B0   = O_W2   + 16777216;       // 16 KiB
  const size_t O_B2   = O_B0   + 16384;          // 16 KiB
  const size_t O_XEMB = O_B2   + 16384;          // 32 MiB
  const size_t O_GATE = O_XEMB + 33554432;       // 64 MiB
  const size_t O_H1   = O_GATE + 67108864;       // 64 MiB
  const size_t O_H2   = O_H1   + 67108864;       // 64 MiB
  const size_t O_C1   = O_H2   + 67108864;       // 256 KiB
  const size_t O_C2   = O_C1   + 262144;         // 256 KiB
  const size_t O_FLG  = O_C2   + 262144;         // flags: l1 8K, l2 8K, gens

  unsigned short* wih0p = (unsigned short*)(ws + O_WIH0);
  unsigned short* whh0p = (unsigned short*)(ws + O_WHH0);
  unsigned short* w2p   = (unsigned short*)(ws + O_W2);
  float* bias0 = (float*)(ws + O_B0);
  float* bias2 = (float*)(ws + O_B2);
  unsigned short* xemb  = (unsigned short*)(ws + O_XEMB);
  unsigned short* gates = (unsigned short*)(ws + O_GATE);
  unsigned short* h1    = (unsigned short*)(ws + O_H1);
  unsigned short* h2    = (unsigned short*)(ws + O_H2);
  float* c1buf = (float*)(ws + O_C1);
  float* c2buf = (float*)(ws + O_C2);
  unsigned* l1flags = (unsigned*)(ws + O_FLG);
  unsigned* l2flags = (unsigned*)(ws + O_FLG + 8192);
  unsigned* l1gen   = (unsigned*)(ws + O_FLG + 16384);
  unsigned* l2gen   = (unsigned*)(ws + O_FLG + 16384 + 128);

  hipMemsetAsync(ws + O_FLG, 0, 20480, stream);

  prep_w_kernel<<<2048, 256, 0, stream>>>(Wih0, wih0p, 7);    // K=512, perm1
  prep_w_kernel<<<4096, 256, 0, stream>>>(Whh0, whh0p, 8);    // K=1024, perm1
  prep_w2_kernel<<<4096, 256, 0, stream>>>(Wih1, w2p, 0);     // perm1, K-offset 0
  prep_w2_kernel<<<4096, 256, 0, stream>>>(Whh1, w2p, 1024);  // perm1, K-offset 1024
  prep_bias_kernel<<<16, 256, 0, stream>>>(bih0, bhh0, bih1, bhh1, bias0, bias2);
  embed_kernel<<<16384, 256, 0, stream>>>(tokens, emb, xemb);

  for (int c = 0; c < 4; ++c) {
    proj_kernel<<<dim3(64, 32), 256, 0, stream>>>(xemb + (size_t)c * MCH * E_, wih0p, bias0, gates, E_);
    fused_kernel<<<130, 256, 0, stream>>>(whh0p, w2p, gates, bias2, h1, h2, c1buf, c2buf,
                                          c * TCH, TCH, l1flags, l2flags, l1gen, l2gen);
  }
  // drain: L2 still owes t=511
  fused_kernel<<<130, 256, 0, stream>>>(whh0p, w2p, gates, bias2, h1, h2, c1buf, c2buf,
                                        512, 1, l1flags, l2flags, l1gen, l2gen);
  head_kernel<<<1, 256, 0, stream>>>(h2 + (size_t)511 * BH, Wd, bd, out);

  (void)in_sizes; (void)n_in; (void)out_size; (void)ws_size;
}

// Round 4
// 5193.339 us; speedup vs baseline: 2.1660x; 2.1660x over previous
//
#include <hip/hip_runtime.h>
#include <stdint.h>

// Problem dims
#define T_   512
#define B_   64
#define E_   512
#define H_   1024
#define G4   4096        // 4*H
#define TCH  128         // T chunk for gates buffer
#define MCH  (TCH*B_)    // 8192 rows per chunk
#define BH   (B_*H_)
#define HSTRIDE (BH + 128)   // +256B pad: sector-fill can't cross step regions

typedef __attribute__((ext_vector_type(8))) short short8;
typedef __attribute__((ext_vector_type(4))) float f32x4;

__device__ __forceinline__ unsigned short f2bf(float f) {
  unsigned u = __builtin_bit_cast(unsigned, f);
  u += 0x7FFFu + ((u >> 16) & 1u);
  return (unsigned short)(u >> 16);
}
__device__ __forceinline__ float bf2f(unsigned short h) {
  return __builtin_bit_cast(float, ((unsigned)h) << 16);
}
__device__ __forceinline__ float sigm(float x) { return 1.f / (1.f + __expf(-x)); }
__device__ __forceinline__ float tanh_f(float x) {
  x = fmaxf(x, -30.f);
  float e = __expf(-2.f * x);
  return (1.f - e) / (1.f + e);
}

// perm1: n = (kblk16, gate, uu16) -> orig = gate*1024 + (n>>6)*16 + (n&15)
__device__ __forceinline__ int perm1_orig(int n) {
  return ((n >> 4) & 3) * 1024 + (n >> 6) * 16 + (n & 15);
}
// perm2: n = (kblk8, gate, uu8) -> orig = gate*1024 + (n>>5)*8 + (n&7)
__device__ __forceinline__ int perm2_orig(int n) {
  return ((n >> 3) & 3) * 1024 + (n >> 5) * 8 + (n & 7);
}

// ---------------- prep: weight convert+permute ----------------
__global__ void prep_w_kernel(const float* __restrict__ src, unsigned short* __restrict__ dst,
                              int kshift) {   // K/4 = 1<<kshift; dst pitch = K, perm1 rows
  const int idx = blockIdx.x * 256 + threadIdx.x;
  const int n = idx >> kshift;
  const int k4 = idx & ((1 << kshift) - 1);
  const int K = 4 << kshift;
  const int orig = perm1_orig(n);
  const float4 v = *((const float4*)(src + (size_t)orig * K) + k4);
  uint2 pk;
  pk.x = (unsigned)f2bf(v.x) | ((unsigned)f2bf(v.y) << 16);
  pk.y = (unsigned)f2bf(v.z) | ((unsigned)f2bf(v.w) << 16);
  *((uint2*)(dst + (size_t)n * K) + k4) = pk;
}

// fused L2 weight: dst[4096][2048] perm2 rows; koff=0 <- Wih1, koff=1024 <- Whh1
__global__ void prep_w2_kernel(const float* __restrict__ src, unsigned short* __restrict__ dst,
                               int koff) {
  const int idx = blockIdx.x * 256 + threadIdx.x;  // 4096 blocks
  const int n = idx >> 8;
  const int k4 = idx & 255;        // K/4 = 256
  const int orig = perm2_orig(n);
  const float4 v = *((const float4*)(src + (size_t)orig * 1024) + k4);
  uint2 pk;
  pk.x = (unsigned)f2bf(v.x) | ((unsigned)f2bf(v.y) << 16);
  pk.y = (unsigned)f2bf(v.z) | ((unsigned)f2bf(v.w) << 16);
  *((uint2*)(dst + (size_t)n * 2048 + koff) + k4) = pk;
}

__global__ void prep_bias_kernel(const float* __restrict__ bih0, const float* __restrict__ bhh0,
                                 const float* __restrict__ bih1, const float* __restrict__ bhh1,
                                 float* __restrict__ b0, float* __restrict__ b2) {
  const int n = blockIdx.x * 256 + threadIdx.x;  // 4096
  const int o1 = perm1_orig(n);
  const int o2 = perm2_orig(n);
  b0[n] = bih0[o1] + bhh0[o1];
  b2[n] = bih1[o2] + bhh1[o2];
}

// ---------------- projection GEMM with fused embedding gather ----------------
// C[m][n] = sum_k emb[tok[m]][k] * Wih0p[n][k] + bias[n];  K=512, C bf16 [MCH][4096]
__global__ __launch_bounds__(256, 2) void proj_kernel(
    const int* __restrict__ tok, const float* __restrict__ emb,
    const unsigned short* __restrict__ Bw,
    const float* __restrict__ bias, unsigned short* __restrict__ Cout) {
  __shared__ unsigned short lsA[128 * 32];
  __shared__ unsigned short lsB[128 * 32];
  const int tid = threadIdx.x;
  const int row0 = blockIdx.x * 128;
  const int col0 = blockIdx.y * 128;
  const int w = tid >> 6, l = tid & 63, l16 = l & 15, kq = l >> 4;
  const int wr = w >> 1, wc = w & 1;
  const int sr = tid >> 2, sc = (tid & 3) * 8;
  f32x4 acc[4][4];
#pragma unroll
  for (int m = 0; m < 4; ++m)
#pragma unroll
    for (int n = 0; n < 4; ++n) acc[m][n] = (f32x4){0.f, 0.f, 0.f, 0.f};

  const int tr1 = tok[row0 + sr];
  const int tr2 = tok[row0 + 64 + sr];
  const float* Ea = emb + (size_t)tr1 * E_ + sc;
  const float* Eb = emb + (size_t)tr2 * E_ + sc;
  const unsigned short* Bb  = Bw + (size_t)(col0 + sr) * E_ + sc;
  const unsigned short* Bb2 = Bb + (size_t)64 * E_;

  for (int k0 = 0; k0 < E_; k0 += 32) {
    float4 a00 = *(const float4*)(Ea + k0), a01 = *(const float4*)(Ea + k0 + 4);
    float4 a10 = *(const float4*)(Eb + k0), a11 = *(const float4*)(Eb + k0 + 4);
    short8 vb0 = *(const short8*)(Bb + k0);
    short8 vb1 = *(const short8*)(Bb2 + k0);
    __syncthreads();
    short8 pa0, pa1;
    pa0[0]=(short)f2bf(a00.x); pa0[1]=(short)f2bf(a00.y); pa0[2]=(short)f2bf(a00.z); pa0[3]=(short)f2bf(a00.w);
    pa0[4]=(short)f2bf(a01.x); pa0[5]=(short)f2bf(a01.y); pa0[6]=(short)f2bf(a01.z); pa0[7]=(short)f2bf(a01.w);
    pa1[0]=(short)f2bf(a10.x); pa1[1]=(short)f2bf(a10.y); pa1[2]=(short)f2bf(a10.z); pa1[3]=(short)f2bf(a10.w);
    pa1[4]=(short)f2bf(a11.x); pa1[5]=(short)f2bf(a11.y); pa1[6]=(short)f2bf(a11.z); pa1[7]=(short)f2bf(a11.w);
    *(short8*)&lsA[sr * 32 + sc] = pa0;
    *(short8*)&lsA[(64 + sr) * 32 + sc] = pa1;
    *(short8*)&lsB[sr * 32 + sc] = vb0;
    *(short8*)&lsB[(64 + sr) * 32 + sc] = vb1;
    __syncthreads();
    short8 af[4], bfr[4];
#pragma unroll
    for (int m = 0; m < 4; ++m) af[m] = *(const short8*)&lsA[(wr * 64 + m * 16 + l16) * 32 + kq * 8];
#pragma unroll
    for (int n = 0; n < 4; ++n) bfr[n] = *(const short8*)&lsB[(wc * 64 + n * 16 + l16) * 32 + kq * 8];
#pragma unroll
    for (int m = 0; m < 4; ++m)
#pragma unroll
      for (int n = 0; n < 4; ++n)
        acc[m][n] = __builtin_amdgcn_mfma_f32_16x16x32_bf16(af[m], bfr[n], acc[m][n], 0, 0, 0);
  }
#pragma unroll
  for (int n = 0; n < 4; ++n) {
    const int col = col0 + wc * 64 + n * 16 + l16;
    const float bv = bias[col];
#pragma unroll
    for (int m = 0; m < 4; ++m)
#pragma unroll
      for (int r = 0; r < 4; ++r) {
        const int row = row0 + wr * 64 + m * 16 + kq * 4 + r;
        Cout[(size_t)row * G4 + col] = f2bf(acc[m][n][r] + bv);
      }
  }
}

// ---------------- per-wave flag poll (relaxed, no fence) ----------------
__device__ __forceinline__ void poll_ge(const unsigned* fp, unsigned tgt) {
  for (;;) {
    unsigned v = __hip_atomic_load(fp, __ATOMIC_RELAXED, __HIP_MEMORY_SCOPE_AGENT);
    if (__all((int)(v >= tgt))) break;
    __builtin_amdgcn_s_sleep(2);
  }
  asm volatile("" ::: "memory");   // compiler fence: h loads stay below
}

// ---------------- fused persistent recurrent kernel ----------------
// grid = 192: bid 0..63   L1 (kblk=bid, 64 perm1 cols, K=1024 from h1[t-1])
//             bid 64..191 L2 (j=bid-64, 32 perm2 cols, K=2048 from [h1[t2]; h2[t2-1]])
// No grid barrier: producers write-through h + set own flag; each consumer WAVE
// polls exactly the flags guarding its own input slice, then plain-loads h
// (first touch is always after the write -> L2 miss -> fresh from IC).
__global__ __launch_bounds__(256, 1) void fused_kernel(
    const unsigned short* __restrict__ Whh0p,   // [4096][1024] perm1
    const unsigned short* __restrict__ W2p,     // [4096][2048] perm2
    const unsigned short* __restrict__ xw,      // [S*64][4096] layer-1 gates chunk
    const float* __restrict__ bias2,            // [4096] perm2
    unsigned short* __restrict__ h1buf, unsigned short* __restrict__ h2buf,
    float* __restrict__ c1buf, float* __restrict__ c2buf,
    int t0, int S,
    unsigned* __restrict__ l1flags, unsigned* __restrict__ l2flags) {
  __shared__ float smem[16 * 64 * 18];   // 73728 B exchange
  const int tid = threadIdx.x, bid = blockIdx.x;
  const int w = tid >> 6, l = tid & 63, l16 = l & 15, kq = l >> 4;

  if (bid < 64) {
    // ================= layer 1 =================
    const int kblk = bid;
    short8 bf[4][8];   // resident weights: 64 cols x 256-K slice = 128 VGPR
#pragma unroll
    for (int st = 0; st < 4; ++st) {
      const unsigned short* bp = Whh0p + (size_t)(kblk * 64 + st * 16 + l16) * H_ + w * 256 + kq * 8;
#pragma unroll
      for (int ks = 0; ks < 8; ++ks) bf[st][ks] = *(const short8*)(bp + ks * 32);
    }
    const int u0 = (tid & 7) * 2, r0 = (tid >> 3) * 2;
    float c00, c01, c10, c11;
    if (t0 == 0) {
      c00 = c01 = c10 = c11 = 0.f;
    } else {
      const float* cb = c1buf + (size_t)r0 * H_ + kblk * 16 + u0;
      c00 = cb[0]; c01 = cb[1]; c10 = cb[H_]; c11 = cb[H_ + 1];
    }
    unsigned xwa[8], xwn[8];
#pragma unroll
    for (int q = 0; q < 8; ++q) xwn[q] = 0;
    if (t0 < T_) {
      const unsigned short* xb = xw + (size_t)r0 * G4 + kblk * 64 + u0;
#pragma unroll
      for (int dr = 0; dr < 2; ++dr)
#pragma unroll
        for (int g = 0; g < 4; ++g) xwa[dr * 4 + g] = *(const unsigned*)(xb + dr * G4 + g * 16);
    }
    for (int s = 0; s < S; ++s) {
      const int t1 = t0 + s;
      if (t1 >= T_) break;
      f32x4 acc[4][4];
#pragma unroll
      for (int rf = 0; rf < 4; ++rf)
#pragma unroll
        for (int st = 0; st < 4; ++st) acc[rf][st] = (f32x4){0.f, 0.f, 0.f, 0.f};
      if (t1 > 0) {
        // wave w consumes h1 cols [w*256, w*256+256) <- producers kblk in [w*16, w*16+16)
        poll_ge(l1flags + (size_t)(w * 16 + (l & 15)) * 32, (unsigned)t1);
        const unsigned short* hp = h1buf + (size_t)(t1 - 1) * HSTRIDE + (size_t)l16 * H_ + w * 256 + kq * 8;
        short8 ah[4][8];
#pragma unroll
        for (int ks = 0; ks < 8; ++ks)
#pragma unroll
          for (int rf = 0; rf < 4; ++rf) ah[rf][ks] = *(const short8*)(hp + rf * 16 * H_ + ks * 32);
#pragma unroll
        for (int ks = 0; ks < 8; ++ks)
#pragma unroll
          for (int st = 0; st < 4; ++st) {
            acc[0][st] = __builtin_amdgcn_mfma_f32_16x16x32_bf16(ah[0][ks], bf[st][ks], acc[0][st], 0, 0, 0);
            acc[1][st] = __builtin_amdgcn_mfma_f32_16x16x32_bf16(ah[1][ks], bf[st][ks], acc[1][st], 0, 0, 0);
            acc[2][st] = __builtin_amdgcn_mfma_f32_16x16x32_bf16(ah[2][ks], bf[st][ks], acc[2][st], 0, 0, 0);
            acc[3][st] = __builtin_amdgcn_mfma_f32_16x16x32_bf16(ah[3][ks], bf[st][ks], acc[3][st], 0, 0, 0);
          }
      }
#pragma unroll
      for (int rf = 0; rf < 4; ++rf)
#pragma unroll
        for (int st = 0; st < 4; ++st)
#pragma unroll
          for (int r = 0; r < 4; ++r)
            smem[(size_t)((w * 4 + st) * 64 + rf * 16 + kq * 4 + r) * 18 + l16] = acc[rf][st][r];
      __syncthreads();   // A: partials ready
      float hv[2][2];
#pragma unroll
      for (int dr = 0; dr < 2; ++dr)
#pragma unroll
        for (int du = 0; du < 2; ++du) {
          const int row = r0 + dr, u = u0 + du;
          float gs[4];
#pragma unroll
          for (int g = 0; g < 4; ++g) {
            gs[g] = smem[(size_t)((0 + g) * 64 + row) * 18 + u]
                  + smem[(size_t)((4 + g) * 64 + row) * 18 + u]
                  + smem[(size_t)((8 + g) * 64 + row) * 18 + u]
                  + smem[(size_t)((12 + g) * 64 + row) * 18 + u]
                  + bf2f((unsigned short)(xwa[dr * 4 + g] >> (du * 16)));
          }
          float iv = sigm(gs[0]), fv = sigm(gs[1]), gv = tanh_f(gs[2]), ov = sigm(gs[3]);
          float& c = dr ? (du ? c11 : c10) : (du ? c01 : c00);
          c = fv * c + iv * gv;
          hv[dr][du] = ov * tanh_f(c);
        }
#pragma unroll
      for (int dr = 0; dr < 2; ++dr) {
        unsigned pk = (unsigned)f2bf(hv[dr][0]) | ((unsigned)f2bf(hv[dr][1]) << 16);
        unsigned* dst = (unsigned*)(h1buf + (size_t)t1 * HSTRIDE + (size_t)(r0 + dr) * H_ + kblk * 16 + u0);
        __hip_atomic_store(dst, pk, __ATOMIC_RELAXED, __HIP_MEMORY_SCOPE_AGENT);
      }
      if (s + 1 < S) {   // prefetch next xw
        const unsigned short* xb = xw + (size_t)(s + 1) * (B_ * G4) + (size_t)r0 * G4 + kblk * 64 + u0;
#pragma unroll
        for (int dr = 0; dr < 2; ++dr)
#pragma unroll
          for (int g = 0; g < 4; ++g) xwn[dr * 4 + g] = *(const unsigned*)(xb + dr * G4 + g * 16);
      }
      __syncthreads();   // B: drains publishes (vmcnt 0) + protects smem reuse
      if (tid == 0)
        __hip_atomic_store(&l1flags[(size_t)kblk * 32], (unsigned)(t1 + 1),
                           __ATOMIC_RELAXED, __HIP_MEMORY_SCOPE_AGENT);
#pragma unroll
      for (int q = 0; q < 8; ++q) xwa[q] = xwn[q];
    }
    if (t0 < T_) {
      float* cb = c1buf + (size_t)r0 * H_ + kblk * 16 + u0;
      cb[0] = c00; cb[1] = c01; cb[H_] = c10; cb[H_ + 1] = c11;
    }
  } else {
    // ================= layer 2 (fused K=2048) =================
    const int j = bid - 64;
    short8 bf2[2][16];  // resident weights: 32 cols x 512-K slice = 128 VGPR
#pragma unroll
    for (int st = 0; st < 2; ++st) {
      const unsigned short* bp = W2p + (size_t)(j * 32 + st * 16 + l16) * 2048 + w * 512 + kq * 8;
#pragma unroll
      for (int ks = 0; ks < 16; ++ks) bf2[st][ks] = *(const short8*)(bp + ks * 32);
    }
    const int u0 = (tid & 3) * 2, r0 = (tid >> 2) * 2;  // valid for tid<128
    float c00, c01, c10, c11;
    float bias_r[2][4];
    if (tid < 128) {
#pragma unroll
      for (int du = 0; du < 2; ++du)
#pragma unroll
        for (int g = 0; g < 4; ++g) bias_r[du][g] = bias2[j * 32 + g * 8 + u0 + du];
      if (t0 == 0) {
        c00 = c01 = c10 = c11 = 0.f;
      } else {
        const float* cb = c2buf + (size_t)r0 * H_ + j * 8 + u0;
        c00 = cb[0]; c01 = cb[1]; c10 = cb[H_]; c11 = cb[H_ + 1];
      }
    }
    for (int s = 0; s < S; ++s) {
      const int t2 = t0 + s - 1;
      if (t2 >= T_) break;
      if (t2 < 0) continue;
      f32x4 acc[4][2];
#pragma unroll
      for (int rf = 0; rf < 4; ++rf)
#pragma unroll
        for (int st = 0; st < 2; ++st) acc[rf][st] = (f32x4){0.f, 0.f, 0.f, 0.f};
      const bool half2 = (w >= 2);
      if (!half2) {
        // waves 0,1: A = h1[t2] cols [w*512,+512) <- l1 producers kblk in [w*32,+32)
        poll_ge(l1flags + (size_t)(w * 32 + (l & 31)) * 32, (unsigned)(t2 + 1));
      } else if (t2 > 0) {
        // waves 2,3: A = h2[t2-1] cols [(w-2)*512,+512) <- l2 producers j in [(w-2)*64,+64)
        poll_ge(l2flags + (size_t)((w - 2) * 64 + l) * 32, (unsigned)t2);
      }
      if (!half2 || t2 > 0) {
        const unsigned short* ap = half2
            ? (h2buf + (size_t)(t2 - 1) * HSTRIDE + (size_t)l16 * H_ + (w - 2) * 512 + kq * 8)
            : (h1buf + (size_t)t2 * HSTRIDE + (size_t)l16 * H_ + w * 512 + kq * 8);
#pragma unroll
        for (int half = 0; half < 2; ++half) {
          short8 ah[4][8];
#pragma unroll
          for (int ks = 0; ks < 8; ++ks)
#pragma unroll
            for (int rf = 0; rf < 4; ++rf)
              ah[rf][ks] = *(const short8*)(ap + rf * 16 * H_ + (half * 8 + ks) * 32);
#pragma unroll
          for (int ks = 0; ks < 8; ++ks)
#pragma unroll
            for (int st = 0; st < 2; ++st) {
              acc[0][st] = __builtin_amdgcn_mfma_f32_16x16x32_bf16(ah[0][ks], bf2[st][half * 8 + ks], acc[0][st], 0, 0, 0);
              acc[1][st] = __builtin_amdgcn_mfma_f32_16x16x32_bf16(ah[1][ks], bf2[st][half * 8 + ks], acc[1][st], 0, 0, 0);
              acc[2][st] = __builtin_amdgcn_mfma_f32_16x16x32_bf16(ah[2][ks], bf2[st][half * 8 + ks], acc[2][st], 0, 0, 0);
              acc[3][st] = __builtin_amdgcn_mfma_f32_16x16x32_bf16(ah[3][ks], bf2[st][half * 8 + ks], acc[3][st], 0, 0, 0);
            }
        }
      }
#pragma unroll
      for (int rf = 0; rf < 4; ++rf)
#pragma unroll
        for (int st = 0; st < 2; ++st)
#pragma unroll
          for (int r = 0; r < 4; ++r)
            smem[(size_t)((w * 2 + st) * 64 + rf * 16 + kq * 4 + r) * 18 + l16] = acc[rf][st][r];
      __syncthreads();   // A
      if (tid < 128) {
        float hv[2][2];
#pragma unroll
        for (int dr = 0; dr < 2; ++dr)
#pragma unroll
          for (int du = 0; du < 2; ++du) {
            const int row = r0 + dr, u = u0 + du;
            float gs[4];
#pragma unroll
            for (int g = 0; g < 4; ++g) {
              const int n = g * 8 + u;
              const int strip = n >> 4, pos = n & 15;
              gs[g] = smem[(size_t)((0 * 2 + strip) * 64 + row) * 18 + pos]
                    + smem[(size_t)((1 * 2 + strip) * 64 + row) * 18 + pos]
                    + smem[(size_t)((2 * 2 + strip) * 64 + row) * 18 + pos]
                    + smem[(size_t)((3 * 2 + strip) * 64 + row) * 18 + pos]
                    + bias_r[du][g];
            }
            float iv = sigm(gs[0]), fv = sigm(gs[1]), gv = tanh_f(gs[2]), ov = sigm(gs[3]);
            float& c = dr ? (du ? c11 : c10) : (du ? c01 : c00);
            c = fv * c + iv * gv;
            hv[dr][du] = ov * tanh_f(c);
          }
#pragma unroll
        for (int dr = 0; dr < 2; ++dr) {
          unsigned pk = (unsigned)f2bf(hv[dr][0]) | ((unsigned)f2bf(hv[dr][1]) << 16);
          unsigned* dst = (unsigned*)(h2buf + (size_t)t2 * HSTRIDE + (size_t)(r0 + dr) * H_ + j * 8 + u0);
          __hip_atomic_store(dst, pk, __ATOMIC_RELAXED, __HIP_MEMORY_SCOPE_AGENT);
        }
      }
      __syncthreads();   // B: drains publishes + protects smem reuse
      if (tid == 0)
        __hip_atomic_store(&l2flags[(size_t)j * 32], (unsigned)(t2 + 1),
                           __ATOMIC_RELAXED, __HIP_MEMORY_SCOPE_AGENT);
    }
    if (tid < 128 && t0 + S - 2 >= 0) {
      float* cb = c2buf + (size_t)r0 * H_ + j * 8 + u0;
      cb[0] = c00; cb[1] = c01; cb[H_] = c10; cb[H_ + 1] = c11;
    }
  }
}

// ---------------- head ----------------
__global__ void head_kernel(const unsigned short* __restrict__ hl, const float* __restrict__ Wd,
                            const float* __restrict__ bdp, float* __restrict__ out) {
  __shared__ float p[256];
  const int tid = threadIdx.x, b = tid >> 2, q = tid & 3;
  const unsigned short* hr = hl + (size_t)b * H_ + q * 256;
  const float* wd = Wd + q * 256;
  float s = 0.f;
#pragma unroll 4
  for (int j = 0; j < 256; j += 8) {
    short8 v = *(const short8*)(hr + j);
#pragma unroll
    for (int i = 0; i < 8; ++i) s += bf2f((unsigned short)v[i]) * wd[j + i];
  }
  p[tid] = s;
  __syncthreads();
  if (q == 0) {
    float tot = p[tid] + p[tid + 1] + p[tid + 2] + p[tid + 3] + bdp[0];
    out[b] = 10.f * sigm(tot);
  }
}

// ---------------- host ----------------
extern "C" void kernel_launch(void* const* d_in, const int* in_sizes, int n_in,
                              void* d_out, int out_size, void* d_ws, size_t ws_size,
                              hipStream_t stream) {
  const int*   tokens = (const int*)d_in[0];
  const float* emb  = (const float*)d_in[1];
  const float* Wih0 = (const float*)d_in[2];
  const float* Whh0 = (const float*)d_in[3];
  const float* bih0 = (const float*)d_in[4];
  const float* bhh0 = (const float*)d_in[5];
  const float* Wih1 = (const float*)d_in[6];
  const float* Whh1 = (const float*)d_in[7];
  const float* bih1 = (const float*)d_in[8];
  const float* bhh1 = (const float*)d_in[9];
  const float* Wd   = (const float*)d_in[10];
  const float* bd   = (const float*)d_in[11];
  float* out = (float*)d_out;
  char* ws = (char*)d_ws;

  // ws layout (bytes), total ~231.5 MiB
  const size_t O_WIH0 = 0;                            // 4 MiB  [4096][512]
  const size_t O_WHH0 = O_WIH0 + 4194304;             // 8 MiB  [4096][1024]
  const size_t O_W2   = O_WHH0 + 8388608;             // 16 MiB [4096][2048]
  const size_t O_B0   = O_W2   + 16777216;            // 16 KiB
  const size_t O_B2   = O_B0   + 16384;               // 16 KiB
  const size_t O_GATE = O_B2   + 16384;               // 64 MiB
  const size_t O_H1   = O_GATE + 67108864;            // 512*HSTRIDE*2 = 67,239,936
  const size_t O_H2   = O_H1   + (size_t)512 * HSTRIDE * 2;
  const size_t O_C1   = O_H2   + (size_t)512 * HSTRIDE * 2;  // 256 KiB
  const size_t O_C2   = O_C1   + 262144;              // 256 KiB
  const size_t O_FLG  = O_C2   + 262144;              // l1 8K + l2 16K

  unsigned short* wih0p = (unsigned short*)(ws + O_WIH0);
  unsigned short* whh0p = (unsigned short*)(ws + O_WHH0);
  unsigned short* w2p   = (unsigned short*)(ws + O_W2);
  float* bias0 = (float*)(ws + O_B0);
  float* bias2 = (float*)(ws + O_B2);
  unsigned short* gates = (unsigned short*)(ws + O_GATE);
  unsigned short* h1    = (unsigned short*)(ws + O_H1);
  unsigned short* h2    = (unsigned short*)(ws + O_H2);
  float* c1buf = (float*)(ws + O_C1);
  float* c2buf = (float*)(ws + O_C2);
  unsigned* l1flags = (unsigned*)(ws + O_FLG);
  unsigned* l2flags = (unsigned*)(ws + O_FLG + 8192);

  hipMemsetAsync(ws + O_FLG, 0, 24576, stream);

  prep_w_kernel<<<2048, 256, 0, stream>>>(Wih0, wih0p, 7);    // K=512, perm1
  prep_w_kernel<<<4096, 256, 0, stream>>>(Whh0, whh0p, 8);    // K=1024, perm1
  prep_w2_kernel<<<4096, 256, 0, stream>>>(Wih1, w2p, 0);     // perm2
  prep_w2_kernel<<<4096, 256, 0, stream>>>(Whh1, w2p, 1024);  // perm2
  prep_bias_kernel<<<16, 256, 0, stream>>>(bih0, bhh0, bih1, bhh1, bias0, bias2);

  for (int c = 0; c < 4; ++c) {
    proj_kernel<<<dim3(64, 32), 256, 0, stream>>>(tokens + (size_t)c * MCH, emb, wih0p, bias0, gates);
    fused_kernel<<<192, 256, 0, stream>>>(whh0p, w2p, gates, bias2, h1, h2, c1buf, c2buf,
                                          c * TCH, TCH, l1flags, l2flags);
  }
  // drain: L2 still owes t=511
  fused_kernel<<<192, 256, 0, stream>>>(whh0p, w2p, gates, bias2, h1, h2, c1buf, c2buf,
                                        512, 1, l1flags, l2flags);
  head_kernel<<<1, 256, 0, stream>>>(h2 + (size_t)511 * HSTRIDE, Wd, bd, out);

  (void)in_sizes; (void)n_in; (void)out_size; (void)ws_size;
}

// Round 5
// 3916.782 us; speedup vs baseline: 2.8720x; 1.3259x over previous
//
#include <hip/hip_runtime.h>
#include <stdint.h>

// Problem dims
#define T_   512
#define B_   64
#define E_   512
#define H_   1024
#define G4   4096        // 4*H
#define TCH  128         // T chunk for gates buffer
#define MCH  (TCH*B_)    // 8192 rows per chunk
#define BH   (B_*H_)
#define HSTRIDE (BH + 128)   // +256B pad per step region

typedef __attribute__((ext_vector_type(8))) short short8;
typedef __attribute__((ext_vector_type(4))) float f32x4;

__device__ __forceinline__ unsigned short f2bf(float f) {
  unsigned u = __builtin_bit_cast(unsigned, f);
  u += 0x7FFFu + ((u >> 16) & 1u);
  return (unsigned short)(u >> 16);
}
__device__ __forceinline__ float bf2f(unsigned short h) {
  return __builtin_bit_cast(float, ((unsigned)h) << 16);
}
__device__ __forceinline__ float sigm(float x) { return 1.f / (1.f + __expf(-x)); }
__device__ __forceinline__ float tanh_f(float x) {
  x = fmaxf(x, -30.f);
  float e = __expf(-2.f * x);
  return (1.f - e) / (1.f + e);
}

// perm1: n = (kblk16, gate, uu16) -> orig = gate*1024 + (n>>6)*16 + (n&15)
__device__ __forceinline__ int perm1_orig(int n) {
  return ((n >> 4) & 3) * 1024 + (n >> 6) * 16 + (n & 15);
}

// ---------------- prep: weight convert+permute ----------------
__global__ void prep_w_kernel(const float* __restrict__ src, unsigned short* __restrict__ dst,
                              int kshift) {   // K/4 = 1<<kshift; dst pitch = K, perm1 rows
  const int idx = blockIdx.x * 256 + threadIdx.x;
  const int n = idx >> kshift;
  const int k4 = idx & ((1 << kshift) - 1);
  const int K = 4 << kshift;
  const int orig = perm1_orig(n);
  const float4 v = *((const float4*)(src + (size_t)orig * K) + k4);
  uint2 pk;
  pk.x = (unsigned)f2bf(v.x) | ((unsigned)f2bf(v.y) << 16);
  pk.y = (unsigned)f2bf(v.z) | ((unsigned)f2bf(v.w) << 16);
  *((uint2*)(dst + (size_t)n * K) + k4) = pk;
}

// fused L2 weight: dst[4096][2048] perm1 rows; koff=0 <- Wih1, koff=1024 <- Whh1
__global__ void prep_w2_kernel(const float* __restrict__ src, unsigned short* __restrict__ dst,
                               int koff) {
  const int idx = blockIdx.x * 256 + threadIdx.x;  // 4096 blocks
  const int n = idx >> 8;
  const int k4 = idx & 255;        // K/4 = 256
  const int orig = perm1_orig(n);
  const float4 v = *((const float4*)(src + (size_t)orig * 1024) + k4);
  uint2 pk;
  pk.x = (unsigned)f2bf(v.x) | ((unsigned)f2bf(v.y) << 16);
  pk.y = (unsigned)f2bf(v.z) | ((unsigned)f2bf(v.w) << 16);
  *((uint2*)(dst + (size_t)n * 2048 + koff) + k4) = pk;
}

__global__ void prep_bias_kernel(const float* __restrict__ bih0, const float* __restrict__ bhh0,
                                 const float* __restrict__ bih1, const float* __restrict__ bhh1,
                                 float* __restrict__ b0, float* __restrict__ b2) {
  const int n = blockIdx.x * 256 + threadIdx.x;  // 4096
  const int o = perm1_orig(n);
  b0[n] = bih0[o] + bhh0[o];
  b2[n] = bih1[o] + bhh1[o];
}

// ---------------- projection GEMM with fused embedding gather ----------------
__global__ __launch_bounds__(256, 2) void proj_kernel(
    const int* __restrict__ tok, const float* __restrict__ emb,
    const unsigned short* __restrict__ Bw,
    const float* __restrict__ bias, unsigned short* __restrict__ Cout) {
  __shared__ unsigned short lsA[128 * 32];
  __shared__ unsigned short lsB[128 * 32];
  const int tid = threadIdx.x;
  const int row0 = blockIdx.x * 128;
  const int col0 = blockIdx.y * 128;
  const int w = tid >> 6, l = tid & 63, l16 = l & 15, kq = l >> 4;
  const int wr = w >> 1, wc = w & 1;
  const int sr = tid >> 2, sc = (tid & 3) * 8;
  f32x4 acc[4][4];
#pragma unroll
  for (int m = 0; m < 4; ++m)
#pragma unroll
    for (int n = 0; n < 4; ++n) acc[m][n] = (f32x4){0.f, 0.f, 0.f, 0.f};

  const int tr1 = tok[row0 + sr];
  const int tr2 = tok[row0 + 64 + sr];
  const float* Ea = emb + (size_t)tr1 * E_ + sc;
  const float* Eb = emb + (size_t)tr2 * E_ + sc;
  const unsigned short* Bb  = Bw + (size_t)(col0 + sr) * E_ + sc;
  const unsigned short* Bb2 = Bb + (size_t)64 * E_;

  for (int k0 = 0; k0 < E_; k0 += 32) {
    float4 a00 = *(const float4*)(Ea + k0), a01 = *(const float4*)(Ea + k0 + 4);
    float4 a10 = *(const float4*)(Eb + k0), a11 = *(const float4*)(Eb + k0 + 4);
    short8 vb0 = *(const short8*)(Bb + k0);
    short8 vb1 = *(const short8*)(Bb2 + k0);
    __syncthreads();
    short8 pa0, pa1;
    pa0[0]=(short)f2bf(a00.x); pa0[1]=(short)f2bf(a00.y); pa0[2]=(short)f2bf(a00.z); pa0[3]=(short)f2bf(a00.w);
    pa0[4]=(short)f2bf(a01.x); pa0[5]=(short)f2bf(a01.y); pa0[6]=(short)f2bf(a01.z); pa0[7]=(short)f2bf(a01.w);
    pa1[0]=(short)f2bf(a10.x); pa1[1]=(short)f2bf(a10.y); pa1[2]=(short)f2bf(a10.z); pa1[3]=(short)f2bf(a10.w);
    pa1[4]=(short)f2bf(a11.x); pa1[5]=(short)f2bf(a11.y); pa1[6]=(short)f2bf(a11.z); pa1[7]=(short)f2bf(a11.w);
    *(short8*)&lsA[sr * 32 + sc] = pa0;
    *(short8*)&lsA[(64 + sr) * 32 + sc] = pa1;
    *(short8*)&lsB[sr * 32 + sc] = vb0;
    *(short8*)&lsB[(64 + sr) * 32 + sc] = vb1;
    __syncthreads();
    short8 af[4], bfr[4];
#pragma unroll
    for (int m = 0; m < 4; ++m) af[m] = *(const short8*)&lsA[(wr * 64 + m * 16 + l16) * 32 + kq * 8];
#pragma unroll
    for (int n = 0; n < 4; ++n) bfr[n] = *(const short8*)&lsB[(wc * 64 + n * 16 + l16) * 32 + kq * 8];
#pragma unroll
    for (int m = 0; m < 4; ++m)
#pragma unroll
      for (int n = 0; n < 4; ++n)
        acc[m][n] = __builtin_amdgcn_mfma_f32_16x16x32_bf16(af[m], bfr[n], acc[m][n], 0, 0, 0);
  }
#pragma unroll
  for (int n = 0; n < 4; ++n) {
    const int col = col0 + wc * 64 + n * 16 + l16;
    const float bv = bias[col];
#pragma unroll
    for (int m = 0; m < 4; ++m)
#pragma unroll
      for (int r = 0; r < 4; ++r) {
        const int row = row0 + wr * 64 + m * 16 + kq * 4 + r;
        Cout[(size_t)row * G4 + col] = f2bf(acc[m][n][r] + bv);
      }
  }
}

// ---------------- one-line flag poll: lanes cover <=16 packed dword flags ----------------
__device__ __forceinline__ void poll_line(const unsigned* fp, unsigned tgt) {
  for (;;) {
    unsigned v = __hip_atomic_load(fp, __ATOMIC_RELAXED, __HIP_MEMORY_SCOPE_AGENT);
    if (__all((int)(v >= tgt))) break;
    __builtin_amdgcn_s_sleep(2);
  }
  asm volatile("" ::: "memory");   // compiler fence: h loads stay below
}

// ---------------- fused persistent recurrent kernel (batch-split G=2) ----------------
// 256 WGs x 512 thr. bid -> (g, idx): q=bid>>3, r=bid&7, g=r>>2, idx=q*4+(r&3).
//   idx<64 : L1 worker (kblk=idx): rows [g*32,+32), cols 64 perm1, K=1024, 8-wave K-split 128.
//   idx>=64: L2 worker (j=idx-64): rows [g*32,+32), cols 64 perm1, K=2048 ([h1[t2];h2[t2-1]]),
//            8-wave K-split 256 (waves 0-3 h1, 4-7 h2).
// Flags: packed dwords l1flags[g*64+kblk], l2flags[g*64+j]; each wave polls the single
// 64B line covering exactly its producers. Publishes are relaxed agent write-through.
__global__ __launch_bounds__(512, 1) void fused_kernel(
    const unsigned short* __restrict__ Whh0p,   // [4096][1024] perm1
    const unsigned short* __restrict__ W2p,     // [4096][2048] perm1
    const unsigned short* __restrict__ xw,      // [S*64][4096] layer-1 gates chunk
    const float* __restrict__ bias2,            // [4096] perm1
    unsigned short* __restrict__ h1buf, unsigned short* __restrict__ h2buf,
    float* __restrict__ c1buf, float* __restrict__ c2buf,
    int t0, int S,
    unsigned* __restrict__ l1flags, unsigned* __restrict__ l2flags) {
  __shared__ float smem[32 * 32 * 18];   // 73728 B: [32 K-strips][32 rows][16 cols pad18]
  const int tid = threadIdx.x, bid = blockIdx.x;
  const int w = tid >> 6, l = tid & 63, l16 = l & 15, kq = l >> 4;
  const int g = (bid >> 2) & 1;
  const int idx = (bid >> 3) * 4 + (bid & 3);
  const int row = tid >> 4;        // elementwise: 0..31
  const int u = tid & 15;
  const int grow = g * 32 + row;

  if (idx < 64) {
    // ================= layer 1 =================
    const int kblk = idx;
    short8 bf[4][4];   // 64 VGPR resident weights: 64 cols x 128-K slice
#pragma unroll
    for (int st = 0; st < 4; ++st) {
      const unsigned short* bp = Whh0p + (size_t)(kblk * 64 + st * 16 + l16) * H_ + w * 128 + kq * 8;
#pragma unroll
      for (int ks = 0; ks < 4; ++ks) bf[st][ks] = *(const short8*)(bp + ks * 32);
    }
    float c0 = 0.f;
    if (t0 > 0) c0 = c1buf[(size_t)grow * H_ + kblk * 16 + u];
    unsigned xcur[4], xnxt[4];
#pragma unroll
    for (int q = 0; q < 4; ++q) xnxt[q] = 0;
    if (t0 < T_) {
      const unsigned short* xb = xw + (size_t)grow * G4 + kblk * 64 + (u & ~1);
#pragma unroll
      for (int gt = 0; gt < 4; ++gt) xcur[gt] = *(const unsigned*)(xb + gt * 16);
    }
    for (int s = 0; s < S; ++s) {
      const int t1 = t0 + s;
      if (t1 >= T_) break;
      f32x4 acc[2][4];
#pragma unroll
      for (int rf = 0; rf < 2; ++rf)
#pragma unroll
        for (int st = 0; st < 4; ++st) acc[rf][st] = (f32x4){0.f, 0.f, 0.f, 0.f};
      if (t1 > 0) {
        // wave w consumes h1 cols [w*128,+128) <- producers kblk in [w*8,+8) (one 64B line)
        poll_line(l1flags + g * 64 + w * 8 + (l & 7), (unsigned)t1);
        const unsigned short* hp = h1buf + (size_t)(t1 - 1) * HSTRIDE + (size_t)(g * 32 + l16) * H_ + w * 128 + kq * 8;
        short8 ah[2][4];
#pragma unroll
        for (int ks = 0; ks < 4; ++ks)
#pragma unroll
          for (int rf = 0; rf < 2; ++rf) ah[rf][ks] = *(const short8*)(hp + rf * 16 * H_ + ks * 32);
#pragma unroll
        for (int ks = 0; ks < 4; ++ks)
#pragma unroll
          for (int st = 0; st < 4; ++st) {
            acc[0][st] = __builtin_amdgcn_mfma_f32_16x16x32_bf16(ah[0][ks], bf[st][ks], acc[0][st], 0, 0, 0);
            acc[1][st] = __builtin_amdgcn_mfma_f32_16x16x32_bf16(ah[1][ks], bf[st][ks], acc[1][st], 0, 0, 0);
          }
      }
#pragma unroll
      for (int rf = 0; rf < 2; ++rf)
#pragma unroll
        for (int st = 0; st < 4; ++st)
#pragma unroll
          for (int r = 0; r < 4; ++r)
            smem[(size_t)((w * 4 + st) * 32 + rf * 16 + kq * 4 + r) * 18 + l16] = acc[rf][st][r];
      __syncthreads();   // A: partials ready
      float gs[4];
#pragma unroll
      for (int gt = 0; gt < 4; ++gt) {
        float t = 0.f;
#pragma unroll
        for (int w2 = 0; w2 < 8; ++w2) t += smem[(size_t)((w2 * 4 + gt) * 32 + row) * 18 + u];
        gs[gt] = t + bf2f((unsigned short)((u & 1) ? (xcur[gt] >> 16) : (xcur[gt] & 0xffff)));
      }
      float iv = sigm(gs[0]), fv = sigm(gs[1]), gv = tanh_f(gs[2]), ov = sigm(gs[3]);
      c0 = fv * c0 + iv * gv;
      float hval = ov * tanh_f(c0);
      unsigned my = (unsigned)f2bf(hval);
      unsigned oth = (unsigned)__shfl_xor((int)my, 1);
      if (!(tid & 1)) {
        unsigned pk = my | (oth << 16);
        unsigned* dst = (unsigned*)(h1buf + (size_t)t1 * HSTRIDE + (size_t)grow * H_ + kblk * 16 + u);
        __hip_atomic_store(dst, pk, __ATOMIC_RELAXED, __HIP_MEMORY_SCOPE_AGENT);
      }
      if (s + 1 < S && t1 + 1 < T_) {  // prefetch next xw during sync slack
        const unsigned short* xb = xw + (size_t)(s + 1) * (B_ * G4) + (size_t)grow * G4 + kblk * 64 + (u & ~1);
#pragma unroll
        for (int gt = 0; gt < 4; ++gt) xnxt[gt] = *(const unsigned*)(xb + gt * 16);
      }
      __syncthreads();   // B: drains publishes (vmcnt 0 per wave) + smem reuse
      if (tid == 0)
        __hip_atomic_store(&l1flags[g * 64 + kblk], (unsigned)(t1 + 1),
                           __ATOMIC_RELAXED, __HIP_MEMORY_SCOPE_AGENT);
#pragma unroll
      for (int q = 0; q < 4; ++q) xcur[q] = xnxt[q];
    }
    if (t0 < T_) c1buf[(size_t)grow * H_ + kblk * 16 + u] = c0;
  } else {
    // ================= layer 2 (fused K=2048) =================
    const int j = idx - 64;
    short8 bf2[4][8];  // 128 VGPR resident weights: 64 cols x 256-K slice
#pragma unroll
    for (int st = 0; st < 4; ++st) {
      const unsigned short* bp = W2p + (size_t)(j * 64 + st * 16 + l16) * 2048 + w * 256 + kq * 8;
#pragma unroll
      for (int ks = 0; ks < 8; ++ks) bf2[st][ks] = *(const short8*)(bp + ks * 32);
    }
    float bias_r[4];
#pragma unroll
    for (int gt = 0; gt < 4; ++gt) bias_r[gt] = bias2[j * 64 + gt * 16 + u];
    float c0 = 0.f;
    if (t0 > 0) c0 = c2buf[(size_t)grow * H_ + j * 16 + u];
    for (int s = 0; s < S; ++s) {
      const int t2 = t0 + s - 1;
      if (t2 >= T_) break;
      if (t2 < 0) continue;
      f32x4 acc[2][4];
#pragma unroll
      for (int rf = 0; rf < 2; ++rf)
#pragma unroll
        for (int st = 0; st < 4; ++st) acc[rf][st] = (f32x4){0.f, 0.f, 0.f, 0.f};
      const bool isH2 = (w >= 4);
      if (!isH2 || t2 > 0) {
        const unsigned short* ap;
        if (!isH2) {
          // h1[t2] cols [w*256,+256) <- l1 producers kblk in [w*16,+16) (one line)
          poll_line(l1flags + g * 64 + w * 16 + l16, (unsigned)(t2 + 1));
          ap = h1buf + (size_t)t2 * HSTRIDE + (size_t)(g * 32 + l16) * H_ + w * 256 + kq * 8;
        } else {
          // h2[t2-1] cols [(w-4)*256,+256) <- l2 producers j in [(w-4)*16,+16)
          poll_line(l2flags + g * 64 + (w - 4) * 16 + l16, (unsigned)t2);
          ap = h2buf + (size_t)(t2 - 1) * HSTRIDE + (size_t)(g * 32 + l16) * H_ + (w - 4) * 256 + kq * 8;
        }
        short8 ah[2][8];
#pragma unroll
        for (int ks = 0; ks < 8; ++ks)
#pragma unroll
          for (int rf = 0; rf < 2; ++rf) ah[rf][ks] = *(const short8*)(ap + rf * 16 * H_ + ks * 32);
#pragma unroll
        for (int ks = 0; ks < 8; ++ks)
#pragma unroll
          for (int st = 0; st < 4; ++st) {
            acc[0][st] = __builtin_amdgcn_mfma_f32_16x16x32_bf16(ah[0][ks], bf2[st][ks], acc[0][st], 0, 0, 0);
            acc[1][st] = __builtin_amdgcn_mfma_f32_16x16x32_bf16(ah[1][ks], bf2[st][ks], acc[1][st], 0, 0, 0);
          }
      }
#pragma unroll
      for (int rf = 0; rf < 2; ++rf)
#pragma unroll
        for (int st = 0; st < 4; ++st)
#pragma unroll
          for (int r = 0; r < 4; ++r)
            smem[(size_t)((w * 4 + st) * 32 + rf * 16 + kq * 4 + r) * 18 + l16] = acc[rf][st][r];
      __syncthreads();   // A
      float gs[4];
#pragma unroll
      for (int gt = 0; gt < 4; ++gt) {
        float t = 0.f;
#pragma unroll
        for (int w2 = 0; w2 < 8; ++w2) t += smem[(size_t)((w2 * 4 + gt) * 32 + row) * 18 + u];
        gs[gt] = t + bias_r[gt];
      }
      float iv = sigm(gs[0]), fv = sigm(gs[1]), gv = tanh_f(gs[2]), ov = sigm(gs[3]);
      c0 = fv * c0 + iv * gv;
      float hval = ov * tanh_f(c0);
      unsigned my = (unsigned)f2bf(hval);
      unsigned oth = (unsigned)__shfl_xor((int)my, 1);
      if (!(tid & 1)) {
        unsigned pk = my | (oth << 16);
        unsigned* dst = (unsigned*)(h2buf + (size_t)t2 * HSTRIDE + (size_t)grow * H_ + j * 16 + u);
        __hip_atomic_store(dst, pk, __ATOMIC_RELAXED, __HIP_MEMORY_SCOPE_AGENT);
      }
      __syncthreads();   // B
      if (tid == 0)
        __hip_atomic_store(&l2flags[g * 64 + j], (unsigned)(t2 + 1),
                           __ATOMIC_RELAXED, __HIP_MEMORY_SCOPE_AGENT);
    }
    if (t0 + S - 2 >= 0 && t0 < T_ + 1) c2buf[(size_t)grow * H_ + j * 16 + u] = c0;
  }
}

// ---------------- head ----------------
__global__ void head_kernel(const unsigned short* __restrict__ hl, const float* __restrict__ Wd,
                            const float* __restrict__ bdp, float* __restrict__ out) {
  __shared__ float p[256];
  const int tid = threadIdx.x, b = tid >> 2, q = tid & 3;
  const unsigned short* hr = hl + (size_t)b * H_ + q * 256;
  const float* wd = Wd + q * 256;
  float s = 0.f;
#pragma unroll 4
  for (int j = 0; j < 256; j += 8) {
    short8 v = *(const short8*)(hr + j);
#pragma unroll
    for (int i = 0; i < 8; ++i) s += bf2f((unsigned short)v[i]) * wd[j + i];
  }
  p[tid] = s;
  __syncthreads();
  if (q == 0) {
    float tot = p[tid] + p[tid + 1] + p[tid + 2] + p[tid + 3] + bdp[0];
    out[b] = 10.f * sigm(tot);
  }
}

// ---------------- host ----------------
extern "C" void kernel_launch(void* const* d_in, const int* in_sizes, int n_in,
                              void* d_out, int out_size, void* d_ws, size_t ws_size,
                              hipStream_t stream) {
  const int*   tokens = (const int*)d_in[0];
  const float* emb  = (const float*)d_in[1];
  const float* Wih0 = (const float*)d_in[2];
  const float* Whh0 = (const float*)d_in[3];
  const float* bih0 = (const float*)d_in[4];
  const float* bhh0 = (const float*)d_in[5];
  const float* Wih1 = (const float*)d_in[6];
  const float* Whh1 = (const float*)d_in[7];
  const float* bih1 = (const float*)d_in[8];
  const float* bhh1 = (const float*)d_in[9];
  const float* Wd   = (const float*)d_in[10];
  const float* bd   = (const float*)d_in[11];
  float* out = (float*)d_out;
  char* ws = (char*)d_ws;

  // ws layout (bytes)
  const size_t O_WIH0 = 0;                            // 4 MiB  [4096][512]
  const size_t O_WHH0 = O_WIH0 + 4194304;             // 8 MiB  [4096][1024]
  const size_t O_W2   = O_WHH0 + 8388608;             // 16 MiB [4096][2048]
  const size_t O_B0   = O_W2   + 16777216;            // 16 KiB
  const size_t O_B2   = O_B0   + 16384;               // 16 KiB
  const size_t O_GATE = O_B2   + 16384;               // 64 MiB
  const size_t O_H1   = O_GATE + 67108864;
  const size_t O_H2   = O_H1   + (size_t)512 * HSTRIDE * 2;
  const size_t O_C1   = O_H2   + (size_t)512 * HSTRIDE * 2;  // 256 KiB
  const size_t O_C2   = O_C1   + 262144;              // 256 KiB
  const size_t O_FLG  = O_C2   + 262144;              // l1 512B + l2 512B packed

  unsigned short* wih0p = (unsigned short*)(ws + O_WIH0);
  unsigned short* whh0p = (unsigned short*)(ws + O_WHH0);
  unsigned short* w2p   = (unsigned short*)(ws + O_W2);
  float* bias0 = (float*)(ws + O_B0);
  float* bias2 = (float*)(ws + O_B2);
  unsigned short* gates = (unsigned short*)(ws + O_GATE);
  unsigned short* h1    = (unsigned short*)(ws + O_H1);
  unsigned short* h2    = (unsigned short*)(ws + O_H2);
  float* c1buf = (float*)(ws + O_C1);
  float* c2buf = (float*)(ws + O_C2);
  unsigned* l1flags = (unsigned*)(ws + O_FLG);
  unsigned* l2flags = (unsigned*)(ws + O_FLG + 512);

  hipMemsetAsync(ws + O_FLG, 0, 4096, stream);

  prep_w_kernel<<<2048, 256, 0, stream>>>(Wih0, wih0p, 7);    // K=512, perm1
  prep_w_kernel<<<4096, 256, 0, stream>>>(Whh0, whh0p, 8);    // K=1024, perm1
  prep_w2_kernel<<<4096, 256, 0, stream>>>(Wih1, w2p, 0);     // perm1
  prep_w2_kernel<<<4096, 256, 0, stream>>>(Whh1, w2p, 1024);  // perm1
  prep_bias_kernel<<<16, 256, 0, stream>>>(bih0, bhh0, bih1, bhh1, bias0, bias2);

  for (int c = 0; c < 4; ++c) {
    proj_kernel<<<dim3(64, 32), 256, 0, stream>>>(tokens + (size_t)c * MCH, emb, wih0p, bias0, gates);
    fused_kernel<<<256, 512, 0, stream>>>(whh0p, w2p, gates, bias2, h1, h2, c1buf, c2buf,
                                          c * TCH, TCH, l1flags, l2flags);
  }
  // drain: L2 still owes t=511
  fused_kernel<<<256, 512, 0, stream>>>(whh0p, w2p, gates, bias2, h1, h2, c1buf, c2buf,
                                        512, 1, l1flags, l2flags);
  head_kernel<<<1, 256, 0, stream>>>(h2 + (size_t)511 * HSTRIDE, Wd, bd, out);

  (void)in_sizes; (void)n_in; (void)out_size; (void)ws_size;
}

// Round 6
// 3465.614 us; speedup vs baseline: 3.2459x; 1.1302x over previous
//
#include <hip/hip_runtime.h>
#include <stdint.h>

// Problem dims
#define T_   512
#define B_   64
#define E_   512
#define H_   1024
#define G4   4096        // 4*H
#define TCH  128         // T chunk for gates buffer
#define MCH  (TCH*B_)    // 8192 rows per chunk
#define BH   (B_*H_)
#define HSTRIDE (BH + 128)   // +256B pad per step region

typedef __attribute__((ext_vector_type(8))) short short8;
typedef __attribute__((ext_vector_type(4))) float f32x4;

__device__ __forceinline__ unsigned short f2bf(float f) {
  unsigned u = __builtin_bit_cast(unsigned, f);
  u += 0x7FFFu + ((u >> 16) & 1u);
  return (unsigned short)(u >> 16);
}
__device__ __forceinline__ float bf2f(unsigned short h) {
  return __builtin_bit_cast(float, ((unsigned)h) << 16);
}
__device__ __forceinline__ float sigm(float x) { return 1.f / (1.f + __expf(-x)); }
__device__ __forceinline__ float tanh_f(float x) {
  x = fmaxf(x, -30.f);
  float e = __expf(-2.f * x);
  return (1.f - e) / (1.f + e);
}

// perm1: n = (kblk16, gate, uu16) -> orig = gate*1024 + (n>>6)*16 + (n&15)
__device__ __forceinline__ int perm1_orig(int n) {
  return ((n >> 4) & 3) * 1024 + (n >> 6) * 16 + (n & 15);
}

// ---------------- prep: weight convert+permute ----------------
__global__ void prep_w_kernel(const float* __restrict__ src, unsigned short* __restrict__ dst,
                              int kshift) {   // K/4 = 1<<kshift; dst pitch = K, perm1 rows
  const int idx = blockIdx.x * 256 + threadIdx.x;
  const int n = idx >> kshift;
  const int k4 = idx & ((1 << kshift) - 1);
  const int K = 4 << kshift;
  const int orig = perm1_orig(n);
  const float4 v = *((const float4*)(src + (size_t)orig * K) + k4);
  uint2 pk;
  pk.x = (unsigned)f2bf(v.x) | ((unsigned)f2bf(v.y) << 16);
  pk.y = (unsigned)f2bf(v.z) | ((unsigned)f2bf(v.w) << 16);
  *((uint2*)(dst + (size_t)n * K) + k4) = pk;
}

// fused L2 weight: dst[4096][2048] perm1 rows; koff=0 <- Wih1, koff=1024 <- Whh1
__global__ void prep_w2_kernel(const float* __restrict__ src, unsigned short* __restrict__ dst,
                               int koff) {
  const int idx = blockIdx.x * 256 + threadIdx.x;  // 4096 blocks
  const int n = idx >> 8;
  const int k4 = idx & 255;        // K/4 = 256
  const int orig = perm1_orig(n);
  const float4 v = *((const float4*)(src + (size_t)orig * 1024) + k4);
  uint2 pk;
  pk.x = (unsigned)f2bf(v.x) | ((unsigned)f2bf(v.y) << 16);
  pk.y = (unsigned)f2bf(v.z) | ((unsigned)f2bf(v.w) << 16);
  *((uint2*)(dst + (size_t)n * 2048 + koff) + k4) = pk;
}

__global__ void prep_bias_kernel(const float* __restrict__ bih0, const float* __restrict__ bhh0,
                                 const float* __restrict__ bih1, const float* __restrict__ bhh1,
                                 float* __restrict__ b0, float* __restrict__ b2) {
  const int n = blockIdx.x * 256 + threadIdx.x;  // 4096
  const int o = perm1_orig(n);
  b0[n] = bih0[o] + bhh0[o];
  b2[n] = bih1[o] + bhh1[o];
}

// ---------------- projection GEMM with fused embedding gather ----------------
__global__ __launch_bounds__(256, 2) void proj_kernel(
    const int* __restrict__ tok, const float* __restrict__ emb,
    const unsigned short* __restrict__ Bw,
    const float* __restrict__ bias, unsigned short* __restrict__ Cout) {
  __shared__ unsigned short lsA[128 * 32];
  __shared__ unsigned short lsB[128 * 32];
  const int tid = threadIdx.x;
  const int row0 = blockIdx.x * 128;
  const int col0 = blockIdx.y * 128;
  const int w = tid >> 6, l = tid & 63, l16 = l & 15, kq = l >> 4;
  const int wr = w >> 1, wc = w & 1;
  const int sr = tid >> 2, sc = (tid & 3) * 8;
  f32x4 acc[4][4];
#pragma unroll
  for (int m = 0; m < 4; ++m)
#pragma unroll
    for (int n = 0; n < 4; ++n) acc[m][n] = (f32x4){0.f, 0.f, 0.f, 0.f};

  const int tr1 = tok[row0 + sr];
  const int tr2 = tok[row0 + 64 + sr];
  const float* Ea = emb + (size_t)tr1 * E_ + sc;
  const float* Eb = emb + (size_t)tr2 * E_ + sc;
  const unsigned short* Bb  = Bw + (size_t)(col0 + sr) * E_ + sc;
  const unsigned short* Bb2 = Bb + (size_t)64 * E_;

  for (int k0 = 0; k0 < E_; k0 += 32) {
    float4 a00 = *(const float4*)(Ea + k0), a01 = *(const float4*)(Ea + k0 + 4);
    float4 a10 = *(const float4*)(Eb + k0), a11 = *(const float4*)(Eb + k0 + 4);
    short8 vb0 = *(const short8*)(Bb + k0);
    short8 vb1 = *(const short8*)(Bb2 + k0);
    __syncthreads();
    short8 pa0, pa1;
    pa0[0]=(short)f2bf(a00.x); pa0[1]=(short)f2bf(a00.y); pa0[2]=(short)f2bf(a00.z); pa0[3]=(short)f2bf(a00.w);
    pa0[4]=(short)f2bf(a01.x); pa0[5]=(short)f2bf(a01.y); pa0[6]=(short)f2bf(a01.z); pa0[7]=(short)f2bf(a01.w);
    pa1[0]=(short)f2bf(a10.x); pa1[1]=(short)f2bf(a10.y); pa1[2]=(short)f2bf(a10.z); pa1[3]=(short)f2bf(a10.w);
    pa1[4]=(short)f2bf(a11.x); pa1[5]=(short)f2bf(a11.y); pa1[6]=(short)f2bf(a11.z); pa1[7]=(short)f2bf(a11.w);
    *(short8*)&lsA[sr * 32 + sc] = pa0;
    *(short8*)&lsA[(64 + sr) * 32 + sc] = pa1;
    *(short8*)&lsB[sr * 32 + sc] = vb0;
    *(short8*)&lsB[(64 + sr) * 32 + sc] = vb1;
    __syncthreads();
    short8 af[4], bfr[4];
#pragma unroll
    for (int m = 0; m < 4; ++m) af[m] = *(const short8*)&lsA[(wr * 64 + m * 16 + l16) * 32 + kq * 8];
#pragma unroll
    for (int n = 0; n < 4; ++n) bfr[n] = *(const short8*)&lsB[(wc * 64 + n * 16 + l16) * 32 + kq * 8];
#pragma unroll
    for (int m = 0; m < 4; ++m)
#pragma unroll
      for (int n = 0; n < 4; ++n)
        acc[m][n] = __builtin_amdgcn_mfma_f32_16x16x32_bf16(af[m], bfr[n], acc[m][n], 0, 0, 0);
  }
#pragma unroll
  for (int n = 0; n < 4; ++n) {
    const int col = col0 + wc * 64 + n * 16 + l16;
    const float bv = bias[col];
#pragma unroll
    for (int m = 0; m < 4; ++m)
#pragma unroll
      for (int r = 0; r < 4; ++r) {
        const int row = row0 + wr * 64 + m * 16 + kq * 4 + r;
        Cout[(size_t)row * G4 + col] = f2bf(acc[m][n][r] + bv);
      }
  }
}

// ---------------- one-line flag poll: lanes cover <=16 packed dword flags ----------------
__device__ __forceinline__ void poll_line(const unsigned* fp, unsigned tgt) {
  for (;;) {
    unsigned v = __hip_atomic_load(fp, __ATOMIC_RELAXED, __HIP_MEMORY_SCOPE_AGENT);
    if (__all((int)(v >= tgt))) break;
    __builtin_amdgcn_s_sleep(1);
  }
  asm volatile("" ::: "memory");   // compiler fence: h loads stay below
}

// ---------------- fused persistent recurrent kernel (batch-split G=2) ----------------
// 256 WGs x 512 thr, LDS 86016 B -> guaranteed 1 WG/CU (2x86016 > 160 KiB).
// bid -> (g, idx): r=bid&7 (XCD on round-robin dispatch), g=r>>2, idx=(bid>>3)*4+(r&3).
//   idx<64 : L1 worker (kblk=idx): rows [g*32,+32), 64 perm1 cols, K=1024, 8-wave K-split.
//   idx>=64: L2 worker (j=idx-64): rows [g*32,+32), 64 perm1 cols, K=2048 ([h1[t2];h2[t2-1]]).
// Publish: relaxed agent write-through stores; flag after barrier-drained h stores;
// consumers poll exactly one 64B flag line, then plain-load h (first touch -> fresh).
__global__ __launch_bounds__(512, 1) void fused_kernel(
    const unsigned short* __restrict__ Whh0p,   // [4096][1024] perm1
    const unsigned short* __restrict__ W2p,     // [4096][2048] perm1
    const unsigned short* __restrict__ xw,      // [TCH*64][4096] layer-1 gates chunk
    const float* __restrict__ bias2,            // [4096] perm1
    unsigned short* __restrict__ h1buf, unsigned short* __restrict__ h2buf,
    float* __restrict__ c1buf, float* __restrict__ c2buf,
    int t0, int S,
    unsigned* __restrict__ l1flags, unsigned* __restrict__ l2flags) {
  __shared__ float smem[21504];   // 86016 B; exchange uses first 32*32*18 floats
  const int tid = threadIdx.x, bid = blockIdx.x;
  const int w = tid >> 6, l = tid & 63, l16 = l & 15, kq = l >> 4;
  const int g = (bid >> 2) & 1;
  const int idx = (bid >> 3) * 4 + (bid & 3);
  const int row = tid >> 4;        // elementwise: 0..31
  const int u = tid & 15;
  const int grow = g * 32 + row;

  if (idx < 64) {
    // ================= layer 1 =================
    const int kblk = idx;
    short8 bf[4][4];   // 64 VGPR resident weights: 64 cols x 128-K slice
#pragma unroll
    for (int st = 0; st < 4; ++st) {
      const unsigned short* bp = Whh0p + (size_t)(kblk * 64 + st * 16 + l16) * H_ + w * 128 + kq * 8;
#pragma unroll
      for (int ks = 0; ks < 4; ++ks) bf[st][ks] = *(const short8*)(bp + ks * 32);
    }
    float c0 = 0.f;
    if (t0 > 0) c0 = c1buf[(size_t)grow * H_ + kblk * 16 + u];
    unsigned xcur[4];
    if (t0 < T_) {
      const unsigned short* xb = xw + (size_t)grow * G4 + kblk * 64 + (u & ~1);
#pragma unroll
      for (int gt = 0; gt < 4; ++gt) xcur[gt] = *(const unsigned*)(xb + gt * 16);
    }
    for (int s = 0; s < S; ++s) {
      const int t1 = t0 + s;
      if (t1 >= T_) break;
      f32x4 acc[2][4];
#pragma unroll
      for (int rf = 0; rf < 2; ++rf)
#pragma unroll
        for (int st = 0; st < 4; ++st) acc[rf][st] = (f32x4){0.f, 0.f, 0.f, 0.f};
      if (t1 > 0) {
        // wave w consumes h1 cols [w*128,+128) <- producers kblk in [w*8,+8) (one 64B line)
        poll_line(l1flags + g * 64 + w * 8 + (l & 7), (unsigned)t1);
        const unsigned short* hp = h1buf + (size_t)(t1 - 1) * HSTRIDE + (size_t)(g * 32 + l16) * H_ + w * 128 + kq * 8;
        short8 ah[2][4];
#pragma unroll
        for (int ks = 0; ks < 4; ++ks)
#pragma unroll
          for (int rf = 0; rf < 2; ++rf) ah[rf][ks] = *(const short8*)(hp + rf * 16 * H_ + ks * 32);
#pragma unroll
        for (int ks = 0; ks < 4; ++ks)
#pragma unroll
          for (int st = 0; st < 4; ++st) {
            acc[0][st] = __builtin_amdgcn_mfma_f32_16x16x32_bf16(ah[0][ks], bf[st][ks], acc[0][st], 0, 0, 0);
            acc[1][st] = __builtin_amdgcn_mfma_f32_16x16x32_bf16(ah[1][ks], bf[st][ks], acc[1][st], 0, 0, 0);
          }
      }
#pragma unroll
      for (int rf = 0; rf < 2; ++rf)
#pragma unroll
        for (int st = 0; st < 4; ++st)
#pragma unroll
          for (int r = 0; r < 4; ++r)
            smem[(size_t)((w * 4 + st) * 32 + rf * 16 + kq * 4 + r) * 18 + l16] = acc[rf][st][r];
      __syncthreads();   // A: partials ready
      float gs[4];
#pragma unroll
      for (int gt = 0; gt < 4; ++gt) {
        float t = 0.f;
#pragma unroll
        for (int w2 = 0; w2 < 8; ++w2) t += smem[(size_t)((w2 * 4 + gt) * 32 + row) * 18 + u];
        gs[gt] = t + bf2f((unsigned short)((u & 1) ? (xcur[gt] >> 16) : (xcur[gt] & 0xffff)));
      }
      float iv = sigm(gs[0]), fv = sigm(gs[1]), gv = tanh_f(gs[2]), ov = sigm(gs[3]);
      c0 = fv * c0 + iv * gv;
      float hval = ov * tanh_f(c0);
      unsigned my = (unsigned)f2bf(hval);
      unsigned oth = (unsigned)__shfl_xor((int)my, 1);
      if (!(tid & 1)) {
        unsigned pk = my | (oth << 16);
        unsigned* dst = (unsigned*)(h1buf + (size_t)t1 * HSTRIDE + (size_t)grow * H_ + kblk * 16 + u);
        __hip_atomic_store(dst, pk, __ATOMIC_RELAXED, __HIP_MEMORY_SCOPE_AGENT);
      }
      __syncthreads();   // B: drains h publishes (vmcnt 0) + protects smem reuse
      if (tid == 0)      // flag publish as early as possible (no pending prefetch!)
        __hip_atomic_store(&l1flags[g * 64 + kblk], (unsigned)(t1 + 1),
                           __ATOMIC_RELAXED, __HIP_MEMORY_SCOPE_AGENT);
      if (s + 1 < S && t1 + 1 < T_) {  // prefetch next xw; overlaps next step's poll
        const unsigned short* xb = xw + (size_t)(s + 1) * (B_ * G4) + (size_t)grow * G4 + kblk * 64 + (u & ~1);
#pragma unroll
        for (int gt = 0; gt < 4; ++gt) xcur[gt] = *(const unsigned*)(xb + gt * 16);
      }
    }
    if (t0 < T_) c1buf[(size_t)grow * H_ + kblk * 16 + u] = c0;
  } else {
    // ================= layer 2 (fused K=2048) =================
    const int j = idx - 64;
    short8 bf2[4][8];  // 128 VGPR resident weights: 64 cols x 256-K slice
#pragma unroll
    for (int st = 0; st < 4; ++st) {
      const unsigned short* bp = W2p + (size_t)(j * 64 + st * 16 + l16) * 2048 + w * 256 + kq * 8;
#pragma unroll
      for (int ks = 0; ks < 8; ++ks) bf2[st][ks] = *(const short8*)(bp + ks * 32);
    }
    float bias_r[4];
#pragma unroll
    for (int gt = 0; gt < 4; ++gt) bias_r[gt] = bias2[j * 64 + gt * 16 + u];
    float c0 = 0.f;
    if (t0 > 0) c0 = c2buf[(size_t)grow * H_ + j * 16 + u];
    for (int s = 0; s < S; ++s) {
      const int t2 = t0 + s - 1;
      if (t2 >= T_) break;
      if (t2 < 0) continue;
      f32x4 acc[2][4];
#pragma unroll
      for (int rf = 0; rf < 2; ++rf)
#pragma unroll
        for (int st = 0; st < 4; ++st) acc[rf][st] = (f32x4){0.f, 0.f, 0.f, 0.f};
      const bool isH2 = (w >= 4);
      if (!isH2 || t2 > 0) {
        const unsigned short* ap;
        if (!isH2) {
          // h1[t2] cols [w*256,+256) <- l1 producers kblk in [w*16,+16) (one line)
          poll_line(l1flags + g * 64 + w * 16 + l16, (unsigned)(t2 + 1));
          ap = h1buf + (size_t)t2 * HSTRIDE + (size_t)(g * 32 + l16) * H_ + w * 256 + kq * 8;
        } else {
          // h2[t2-1] cols [(w-4)*256,+256) <- l2 producers j in [(w-4)*16,+16)
          poll_line(l2flags + g * 64 + (w - 4) * 16 + l16, (unsigned)t2);
          ap = h2buf + (size_t)(t2 - 1) * HSTRIDE + (size_t)(g * 32 + l16) * H_ + (w - 4) * 256 + kq * 8;
        }
        short8 ah[2][8];
#pragma unroll
        for (int ks = 0; ks < 8; ++ks)
#pragma unroll
          for (int rf = 0; rf < 2; ++rf) ah[rf][ks] = *(const short8*)(ap + rf * 16 * H_ + ks * 32);
#pragma unroll
        for (int ks = 0; ks < 8; ++ks)
#pragma unroll
          for (int st = 0; st < 4; ++st) {
            acc[0][st] = __builtin_amdgcn_mfma_f32_16x16x32_bf16(ah[0][ks], bf2[st][ks], acc[0][st], 0, 0, 0);
            acc[1][st] = __builtin_amdgcn_mfma_f32_16x16x32_bf16(ah[1][ks], bf2[st][ks], acc[1][st], 0, 0, 0);
          }
      }
#pragma unroll
      for (int rf = 0; rf < 2; ++rf)
#pragma unroll
        for (int st = 0; st < 4; ++st)
#pragma unroll
          for (int r = 0; r < 4; ++r)
            smem[(size_t)((w * 4 + st) * 32 + rf * 16 + kq * 4 + r) * 18 + l16] = acc[rf][st][r];
      __syncthreads();   // A
      float gs[4];
#pragma unroll
      for (int gt = 0; gt < 4; ++gt) {
        float t = 0.f;
#pragma unroll
        for (int w2 = 0; w2 < 8; ++w2) t += smem[(size_t)((w2 * 4 + gt) * 32 + row) * 18 + u];
        gs[gt] = t + bias_r[gt];
      }
      float iv = sigm(gs[0]), fv = sigm(gs[1]), gv = tanh_f(gs[2]), ov = sigm(gs[3]);
      c0 = fv * c0 + iv * gv;
      float hval = ov * tanh_f(c0);
      unsigned my = (unsigned)f2bf(hval);
      unsigned oth = (unsigned)__shfl_xor((int)my, 1);
      if (!(tid & 1)) {
        unsigned pk = my | (oth << 16);
        unsigned* dst = (unsigned*)(h2buf + (size_t)t2 * HSTRIDE + (size_t)grow * H_ + j * 16 + u);
        __hip_atomic_store(dst, pk, __ATOMIC_RELAXED, __HIP_MEMORY_SCOPE_AGENT);
      }
      __syncthreads();   // B: drains h2 publishes
      if (tid == 0)
        __hip_atomic_store(&l2flags[g * 64 + j], (unsigned)(t2 + 1),
                           __ATOMIC_RELAXED, __HIP_MEMORY_SCOPE_AGENT);
    }
    if (t0 + S - 2 >= 0 && t0 < T_ + 1) c2buf[(size_t)grow * H_ + j * 16 + u] = c0;
  }
}

// ---------------- head ----------------
__global__ void head_kernel(const unsigned short* __restrict__ hl, const float* __restrict__ Wd,
                            const float* __restrict__ bdp, float* __restrict__ out) {
  __shared__ float p[256];
  const int tid = threadIdx.x, b = tid >> 2, q = tid & 3;
  const unsigned short* hr = hl + (size_t)b * H_ + q * 256;
  const float* wd = Wd + q * 256;
  float s = 0.f;
#pragma unroll 4
  for (int j = 0; j < 256; j += 8) {
    short8 v = *(const short8*)(hr + j);
#pragma unroll
    for (int i = 0; i < 8; ++i) s += bf2f((unsigned short)v[i]) * wd[j + i];
  }
  p[tid] = s;
  __syncthreads();
  if (q == 0) {
    float tot = p[tid] + p[tid + 1] + p[tid + 2] + p[tid + 3] + bdp[0];
    out[b] = 10.f * sigm(tot);
  }
}

// ---------------- host ----------------
extern "C" void kernel_launch(void* const* d_in, const int* in_sizes, int n_in,
                              void* d_out, int out_size, void* d_ws, size_t ws_size,
                              hipStream_t stream) {
  const int*   tokens = (const int*)d_in[0];
  const float* emb  = (const float*)d_in[1];
  const float* Wih0 = (const float*)d_in[2];
  const float* Whh0 = (const float*)d_in[3];
  const float* bih0 = (const float*)d_in[4];
  const float* bhh0 = (const float*)d_in[5];
  const float* Wih1 = (const float*)d_in[6];
  const float* Whh1 = (const float*)d_in[7];
  const float* bih1 = (const float*)d_in[8];
  const float* bhh1 = (const float*)d_in[9];
  const float* Wd   = (const float*)d_in[10];
  const float* bd   = (const float*)d_in[11];
  float* out = (float*)d_out;
  char* ws = (char*)d_ws;

  // ws layout (bytes)
  const size_t O_WIH0 = 0;                            // 4 MiB  [4096][512]
  const size_t O_WHH0 = O_WIH0 + 4194304;             // 8 MiB  [4096][1024]
  const size_t O_W2   = O_WHH0 + 8388608;             // 16 MiB [4096][2048]
  const size_t O_B0   = O_W2   + 16777216;            // 16 KiB
  const size_t O_B2   = O_B0   + 16384;               // 16 KiB
  const size_t O_GATE = O_B2   + 16384;               // 64 MiB
  const size_t O_H1   = O_GATE + 67108864;
  const size_t O_H2   = O_H1   + (size_t)512 * HSTRIDE * 2;
  const size_t O_C1   = O_H2   + (size_t)512 * HSTRIDE * 2;  // 256 KiB
  const size_t O_C2   = O_C1   + 262144;              // 256 KiB
  const size_t O_FLG  = O_C2   + 262144;              // l1 512B + l2 512B packed

  unsigned short* wih0p = (unsigned short*)(ws + O_WIH0);
  unsigned short* whh0p = (unsigned short*)(ws + O_WHH0);
  unsigned short* w2p   = (unsigned short*)(ws + O_W2);
  float* bias0 = (float*)(ws + O_B0);
  float* bias2 = (float*)(ws + O_B2);
  unsigned short* gates = (unsigned short*)(ws + O_GATE);
  unsigned short* h1    = (unsigned short*)(ws + O_H1);
  unsigned short* h2    = (unsigned short*)(ws + O_H2);
  float* c1buf = (float*)(ws + O_C1);
  float* c2buf = (float*)(ws + O_C2);
  unsigned* l1flags = (unsigned*)(ws + O_FLG);
  unsigned* l2flags = (unsigned*)(ws + O_FLG + 512);

  hipMemsetAsync(ws + O_FLG, 0, 4096, stream);

  prep_w_kernel<<<2048, 256, 0, stream>>>(Wih0, wih0p, 7);    // K=512, perm1
  prep_w_kernel<<<4096, 256, 0, stream>>>(Whh0, whh0p, 8);    // K=1024, perm1
  prep_w2_kernel<<<4096, 256, 0, stream>>>(Wih1, w2p, 0);     // perm1
  prep_w2_kernel<<<4096, 256, 0, stream>>>(Whh1, w2p, 1024);  // perm1
  prep_bias_kernel<<<16, 256, 0, stream>>>(bih0, bhh0, bih1, bhh1, bias0, bias2);

  for (int c = 0; c < 4; ++c) {
    proj_kernel<<<dim3(64, 32), 256, 0, stream>>>(tokens + (size_t)c * MCH, emb, wih0p, bias0, gates);
    // last chunk runs one extra macro-step so L2 finishes t=511 (no drain launch)
    const int S = (c == 3) ? (TCH + 1) : TCH;
    fused_kernel<<<256, 512, 0, stream>>>(whh0p, w2p, gates, bias2, h1, h2, c1buf, c2buf,
                                          c * TCH, S, l1flags, l2flags);
  }
  head_kernel<<<1, 256, 0, stream>>>(h2 + (size_t)511 * HSTRIDE, Wd, bd, out);

  (void)in_sizes; (void)n_in; (void)out_size; (void)ws_size;
}